// Round 1
// baseline (1259.164 us; speedup 1.0000x reference)
//
#include <hip/hip_runtime.h>
#include <math.h>

#define DIM 1024
#define NH 16
#define HD 64
#define NB 2
#define SEQ 2048

// ---------------------------------------------------------------------------
// quad (4-lane) sum via DPP quad_perm: lanes grouped as c = tid&3
// ---------------------------------------------------------------------------
__device__ __forceinline__ float quad_sum(float x) {
    int y = __builtin_amdgcn_mov_dpp(__float_as_int(x), 0xB1, 0xF, 0xF, true); // xor 1
    x += __int_as_float(y);
    y = __builtin_amdgcn_mov_dpp(__float_as_int(x), 0x4E, 0xF, 0xF, true);     // xor 2
    x += __int_as_float(y);
    return x;
}

// ---------------------------------------------------------------------------
// GEMM: C[m,n] = sum_k X[m,k] * W[n,k]   (torch Linear, y = x @ W.T)
// X: [4096,1024] rm, W: [1024,1024] rm.
// MODE 0: blockIdx.z selects (W0,O0)/(W1,O1)/(W2,O2), head-split out [b,h,s,hd]
// MODE 1: flat out [b,s,e]
// tile 64x64, BK=32. 256 thr, 4x4 micro-tile. LDS stored transposed [k][row].
// ---------------------------------------------------------------------------
template<int MODE>
__global__ __launch_bounds__(256)
void gemm_kernel(const float* __restrict__ X,
                 const float* __restrict__ W0,
                 const float* __restrict__ W1,
                 const float* __restrict__ W2,
                 float* __restrict__ O0,
                 float* __restrict__ O1,
                 float* __restrict__ O2)
{
    __shared__ float AsT[32][68];
    __shared__ float BsT[32][68];

    const float* W;
    float* O;
    if (MODE == 0) {
        const int z = blockIdx.z;
        W = (z == 0) ? W0 : (z == 1) ? W1 : W2;
        O = (z == 0) ? O0 : (z == 1) ? O1 : O2;
    } else {
        W = W0; O = O0;
    }

    const int t  = threadIdx.x;
    const int tx = t & 15;         // n micro
    const int ty = t >> 4;         // m micro
    const int m_base = blockIdx.x * 64;
    const int n_base = blockIdx.y * 64;

    const int lrow = t >> 3;       // 0..31
    const int lc4  = (t & 7) << 2; // 0..28

    const float* Xb = X + (size_t)m_base * DIM;
    const float* Wb = W + (size_t)n_base * DIM;

    float acc[4][4] = {};

    for (int k0 = 0; k0 < DIM; k0 += 32) {
        float4 a0 = *(const float4*)(Xb + (size_t)lrow * DIM + k0 + lc4);
        float4 a1 = *(const float4*)(Xb + (size_t)(lrow + 32) * DIM + k0 + lc4);
        float4 b0 = *(const float4*)(Wb + (size_t)lrow * DIM + k0 + lc4);
        float4 b1 = *(const float4*)(Wb + (size_t)(lrow + 32) * DIM + k0 + lc4);
        __syncthreads();
        AsT[lc4+0][lrow]    = a0.x; AsT[lc4+1][lrow]    = a0.y;
        AsT[lc4+2][lrow]    = a0.z; AsT[lc4+3][lrow]    = a0.w;
        AsT[lc4+0][lrow+32] = a1.x; AsT[lc4+1][lrow+32] = a1.y;
        AsT[lc4+2][lrow+32] = a1.z; AsT[lc4+3][lrow+32] = a1.w;
        BsT[lc4+0][lrow]    = b0.x; BsT[lc4+1][lrow]    = b0.y;
        BsT[lc4+2][lrow]    = b0.z; BsT[lc4+3][lrow]    = b0.w;
        BsT[lc4+0][lrow+32] = b1.x; BsT[lc4+1][lrow+32] = b1.y;
        BsT[lc4+2][lrow+32] = b1.z; BsT[lc4+3][lrow+32] = b1.w;
        __syncthreads();
        #pragma unroll 8
        for (int kk = 0; kk < 32; ++kk) {
            float4 av = *(const float4*)&AsT[kk][ty << 2];
            float4 bv = *(const float4*)&BsT[kk][tx << 2];
            float a[4] = {av.x, av.y, av.z, av.w};
            float b[4] = {bv.x, bv.y, bv.z, bv.w};
            #pragma unroll
            for (int i = 0; i < 4; ++i)
                #pragma unroll
                for (int j = 0; j < 4; ++j)
                    acc[i][j] = fmaf(a[i], b[j], acc[i][j]);
        }
    }

    #pragma unroll
    for (int i = 0; i < 4; ++i) {
        const int m = m_base + (ty << 2) + i;
        const int b = m >> 11;            // / SEQ
        const int s = m & (SEQ - 1);
        float4 val = make_float4(acc[i][0], acc[i][1], acc[i][2], acc[i][3]);
        if (MODE == 0) {
            const int head = blockIdx.y;  // n-tile width 64 == HD, D/64 == NH
            *(float4*)(O + ((((size_t)b * NH + head) * SEQ + s) * HD + (tx << 2))) = val;
        } else {
            *(float4*)(O + (((size_t)b * SEQ + s) * DIM + n_base + (tx << 2))) = val;
        }
    }
}

// ---------------------------------------------------------------------------
// Attention + memory-read + gated combine.
// Block: (qt, h, b); 256 threads; 128 q-rows per block (rows rr and rr+64).
// lane: c = t&3 owns d-slice [16c,16c+16); rr = t>>2.
// Online softmax, K-tile 64, scores in regs in chunks of 32 (fully unrolled).
// Epilogue: q_mem = elu(q)+1 staged in LDS, mem_out = q_mem @ M, combine, store.
// ---------------------------------------------------------------------------
__global__ __launch_bounds__(256)
void attn_kernel(const float* __restrict__ q,
                 const float* __restrict__ k,
                 const float* __restrict__ v,
                 const float* __restrict__ memv,
                 const float* __restrict__ normv,
                 const float* __restrict__ gatev,
                 float* __restrict__ combined)
{
    __shared__ float Ks[64][68];
    __shared__ float Vs[64][68];
    __shared__ float Ms[64][68];
    __shared__ float norm_s[64];

    const int qt = blockIdx.x;     // 0..15
    const int h  = blockIdx.y;     // 0..15
    const int b  = blockIdx.z;     // 0..1
    const int t  = threadIdx.x;
    const int c  = t & 3;
    const int rr = t >> 2;         // 0..63
    const int d0 = c << 4;

    const size_t bh = (size_t)b * NH + h;
    const float* qb = q + bh * SEQ * HD;
    const float* kb = k + bh * SEQ * HD;
    const float* vb = v + bh * SEQ * HD;

    const int qbase = qt * 128;
    const int row0 = qbase + rr;
    const int row1 = qbase + rr + 64;

    // stage memory matrix M (64x64) and norm vector
    {
        const float* Mb = memv + bh * HD * HD;
        #pragma unroll
        for (int u = 0; u < 4; ++u) {
            int f  = t + (u << 8);
            int r_ = f >> 4;
            int c4 = (f & 15) << 2;
            *(float4*)&Ms[r_][c4] = *(const float4*)(Mb + r_ * HD + c4);
        }
        if (t < 64) norm_s[t] = normv[bh * HD + t];
    }

    // q rows into registers
    float q0[16], q1[16];
    #pragma unroll
    for (int u = 0; u < 4; ++u) {
        float4 x0 = *(const float4*)(qb + (size_t)row0 * HD + d0 + (u << 2));
        float4 x1 = *(const float4*)(qb + (size_t)row1 * HD + d0 + (u << 2));
        q0[4*u+0] = x0.x; q0[4*u+1] = x0.y; q0[4*u+2] = x0.z; q0[4*u+3] = x0.w;
        q1[4*u+0] = x1.x; q1[4*u+1] = x1.y; q1[4*u+2] = x1.z; q1[4*u+3] = x1.w;
    }

    float o0[16] = {}, o1[16] = {};
    float m0 = -1e30f, m1 = -1e30f, l0 = 0.f, l1 = 0.f;

    const int ntiles = 2 * qt + 2;
    for (int kt = 0; kt < ntiles; ++kt) {
        __syncthreads();
        #pragma unroll
        for (int u = 0; u < 4; ++u) {
            int f  = t + (u << 8);
            int r_ = f >> 4;
            int c4 = (f & 15) << 2;
            *(float4*)&Ks[r_][c4] = *(const float4*)(kb + ((size_t)(kt*64 + r_)) * HD + c4);
            *(float4*)&Vs[r_][c4] = *(const float4*)(vb + ((size_t)(kt*64 + r_)) * HD + c4);
        }
        __syncthreads();

        for (int ch = 0; ch < 2; ++ch) {
            float sc0[32], sc1[32];
            float cm0 = -1e30f, cm1 = -1e30f;
            #pragma unroll
            for (int j = 0; j < 32; ++j) {
                const int jj = (ch << 5) + j;
                float f0 = 0.f, f1 = 0.f;
                #pragma unroll
                for (int u = 0; u < 4; ++u) {
                    float4 kv = *(const float4*)&Ks[jj][d0 + (u << 2)];
                    f0 = fmaf(q0[4*u+0], kv.x, f0);
                    f0 = fmaf(q0[4*u+1], kv.y, f0);
                    f0 = fmaf(q0[4*u+2], kv.z, f0);
                    f0 = fmaf(q0[4*u+3], kv.w, f0);
                    f1 = fmaf(q1[4*u+0], kv.x, f1);
                    f1 = fmaf(q1[4*u+1], kv.y, f1);
                    f1 = fmaf(q1[4*u+2], kv.z, f1);
                    f1 = fmaf(q1[4*u+3], kv.w, f1);
                }
                f0 = quad_sum(f0) * 0.125f;
                f1 = quad_sum(f1) * 0.125f;
                const int kg = kt * 64 + jj;
                f0 = (kg <= row0) ? f0 : -1e30f;
                f1 = (kg <= row1) ? f1 : -1e30f;
                sc0[j] = f0; sc1[j] = f1;
                cm0 = fmaxf(cm0, f0); cm1 = fmaxf(cm1, f1);
            }
            const float mn0 = fmaxf(m0, cm0);
            const float mn1 = fmaxf(m1, cm1);
            const float corr0 = __expf(m0 - mn0);
            const float corr1 = __expf(m1 - mn1);
            l0 *= corr0; l1 *= corr1;
            #pragma unroll
            for (int i = 0; i < 16; ++i) { o0[i] *= corr0; o1[i] *= corr1; }
            m0 = mn0; m1 = mn1;
            #pragma unroll
            for (int j = 0; j < 32; ++j) {
                const int jj = (ch << 5) + j;
                const float p0 = __expf(sc0[j] - m0);
                const float p1 = __expf(sc1[j] - m1);
                l0 += p0; l1 += p1;
                #pragma unroll
                for (int u = 0; u < 4; ++u) {
                    float4 vv = *(const float4*)&Vs[jj][d0 + (u << 2)];
                    o0[4*u+0] = fmaf(p0, vv.x, o0[4*u+0]);
                    o0[4*u+1] = fmaf(p0, vv.y, o0[4*u+1]);
                    o0[4*u+2] = fmaf(p0, vv.z, o0[4*u+2]);
                    o0[4*u+3] = fmaf(p0, vv.w, o0[4*u+3]);
                    o1[4*u+0] = fmaf(p1, vv.x, o1[4*u+0]);
                    o1[4*u+1] = fmaf(p1, vv.y, o1[4*u+1]);
                    o1[4*u+2] = fmaf(p1, vv.z, o1[4*u+2]);
                    o1[4*u+3] = fmaf(p1, vv.w, o1[4*u+3]);
                }
            }
        }
    }

    const float invl0 = 1.f / l0;
    const float invl1 = 1.f / l1;

    // stage q_mem = elu(q)+1 : rows 0..63 -> Ks, rows 64..127 -> Vs
    __syncthreads();
    #pragma unroll
    for (int i = 0; i < 16; ++i) {
        const float x0 = q0[i], x1 = q1[i];
        Ks[rr][d0 + i] = (x0 > 0.f) ? (x0 + 1.f) : __expf(x0);
        Vs[rr][d0 + i] = (x1 > 0.f) ? (x1 + 1.f) : __expf(x1);
    }
    __syncthreads();

    float ma0[16] = {}, ma1[16] = {};
    float nr0 = 0.f, nr1 = 0.f;
    for (int d = 0; d < 64; ++d) {
        const float qv0 = Ks[rr][d];
        const float qv1 = Vs[rr][d];
        const float nw  = norm_s[d];
        nr0 = fmaf(qv0, nw, nr0);
        nr1 = fmaf(qv1, nw, nr1);
        #pragma unroll
        for (int u = 0; u < 4; ++u) {
            float4 mv = *(const float4*)&Ms[d][d0 + (u << 2)];
            ma0[4*u+0] = fmaf(qv0, mv.x, ma0[4*u+0]);
            ma0[4*u+1] = fmaf(qv0, mv.y, ma0[4*u+1]);
            ma0[4*u+2] = fmaf(qv0, mv.z, ma0[4*u+2]);
            ma0[4*u+3] = fmaf(qv0, mv.w, ma0[4*u+3]);
            ma1[4*u+0] = fmaf(qv1, mv.x, ma1[4*u+0]);
            ma1[4*u+1] = fmaf(qv1, mv.y, ma1[4*u+1]);
            ma1[4*u+2] = fmaf(qv1, mv.z, ma1[4*u+2]);
            ma1[4*u+3] = fmaf(qv1, mv.w, ma1[4*u+3]);
        }
    }

    const float g = 1.f / (1.f + __expf(-gatev[h]));
    const float og = 1.f - g;
    const float inv_n0 = 1.f / (nr0 + 1e-6f);
    const float inv_n1 = 1.f / (nr1 + 1e-6f);

    float* crow0 = combined + ((size_t)b * SEQ + row0) * DIM + h * HD + d0;
    float* crow1 = combined + ((size_t)b * SEQ + row1) * DIM + h * HD + d0;
    #pragma unroll
    for (int u = 0; u < 4; ++u) {
        float4 w0, w1;
        w0.x = g * (ma0[4*u+0] * inv_n0) + og * (o0[4*u+0] * invl0);
        w0.y = g * (ma0[4*u+1] * inv_n0) + og * (o0[4*u+1] * invl0);
        w0.z = g * (ma0[4*u+2] * inv_n0) + og * (o0[4*u+2] * invl0);
        w0.w = g * (ma0[4*u+3] * inv_n0) + og * (o0[4*u+3] * invl0);
        w1.x = g * (ma1[4*u+0] * inv_n1) + og * (o1[4*u+0] * invl1);
        w1.y = g * (ma1[4*u+1] * inv_n1) + og * (o1[4*u+1] * invl1);
        w1.z = g * (ma1[4*u+2] * inv_n1) + og * (o1[4*u+2] * invl1);
        w1.w = g * (ma1[4*u+3] * inv_n1) + og * (o1[4*u+3] * invl1);
        *(float4*)(crow0 + (u << 2)) = w0;
        *(float4*)(crow1 + (u << 2)) = w1;
    }
}

// ---------------------------------------------------------------------------
// Memory write: new_mem[bh,d,e] = mem + sum_s (elu(k)+1)[s,d] * v[s,e]
//               new_norm[bh,d]  = norm + sum_s (elu(k)+1)[s,d]
// One 1024-thread block per (b,h). thread: d = t>>4, e-slice (t&15)*4.
// ---------------------------------------------------------------------------
__global__ __launch_bounds__(1024)
void memwrite_kernel(const float* __restrict__ k,
                     const float* __restrict__ v,
                     const float* __restrict__ memv,
                     const float* __restrict__ normv,
                     float* __restrict__ new_mem,
                     float* __restrict__ new_norm)
{
    __shared__ float Ks[64][68];
    __shared__ float Vs[64][68];

    const int bh = blockIdx.x;   // 0..31
    const int t  = threadIdx.x;  // 0..1023
    const int dr = t >> 4;       // 0..63
    const int c  = t & 15;
    const int e0 = c << 2;

    const float* kb = k + (size_t)bh * SEQ * HD;
    const float* vb = v + (size_t)bh * SEQ * HD;

    float acc[4] = {};
    float nacc = 0.f;

    for (int st = 0; st < SEQ / 64; ++st) {
        __syncthreads();
        {
            const int r_ = t >> 4;
            const int c4 = (t & 15) << 2;
            *(float4*)&Ks[r_][c4] = *(const float4*)(kb + ((size_t)(st*64 + r_)) * HD + c4);
            *(float4*)&Vs[r_][c4] = *(const float4*)(vb + ((size_t)(st*64 + r_)) * HD + c4);
        }
        __syncthreads();
        #pragma unroll 8
        for (int ss = 0; ss < 64; ++ss) {
            const float kraw = Ks[ss][dr];
            const float km = (kraw > 0.f) ? (kraw + 1.f) : __expf(kraw);
            nacc += km;
            float4 vv = *(const float4*)&Vs[ss][e0];
            acc[0] = fmaf(km, vv.x, acc[0]);
            acc[1] = fmaf(km, vv.y, acc[1]);
            acc[2] = fmaf(km, vv.z, acc[2]);
            acc[3] = fmaf(km, vv.w, acc[3]);
        }
    }

    const size_t off = ((size_t)bh * HD + dr) * HD + e0;
    float4 mold = *(const float4*)(memv + off);
    float4 outv = make_float4(mold.x + acc[0], mold.y + acc[1],
                              mold.z + acc[2], mold.w + acc[3]);
    *(float4*)(new_mem + off) = outv;
    if (c == 0) new_norm[(size_t)bh * HD + dr] = normv[(size_t)bh * HD + dr] + nacc;
}

// ---------------------------------------------------------------------------
extern "C" void kernel_launch(void* const* d_in, const int* in_sizes, int n_in,
                              void* d_out, int out_size, void* d_ws, size_t ws_size,
                              hipStream_t stream)
{
    const float* x     = (const float*)d_in[0];
    const float* memv  = (const float*)d_in[1];
    const float* normv = (const float*)d_in[2];
    const float* Wq    = (const float*)d_in[3];
    const float* Wk    = (const float*)d_in[4];
    const float* Wv    = (const float*)d_in[5];
    const float* Wo    = (const float*)d_in[6];
    const float* gate  = (const float*)d_in[7];
    float* out = (float*)d_out;

    const size_t NQ = (size_t)NB * NH * SEQ * HD;   // 4,194,304 per buffer
    float* q    = (float*)d_ws;
    float* kbuf = q + NQ;
    float* vbuf = kbuf + NQ;
    float* comb = vbuf + NQ;

    float* new_mem  = out + (size_t)NB * SEQ * DIM;               // +4,194,304
    float* new_norm = new_mem + (size_t)NB * NH * HD * HD;        // +131,072

    // 1) QKV projections (head-split layout [b,h,s,hd])
    gemm_kernel<0><<<dim3(64, 16, 3), 256, 0, stream>>>(x, Wq, Wk, Wv, q, kbuf, vbuf);
    // 2) causal attention + memory read + gated combine -> comb [b,s,D]
    attn_kernel<<<dim3(16, 16, 2), 256, 0, stream>>>(q, kbuf, vbuf, memv, normv, gate, comb);
    // 3) memory write -> d_out tail
    memwrite_kernel<<<dim3(32), 1024, 0, stream>>>(kbuf, vbuf, memv, normv, new_mem, new_norm);
    // 4) output projection -> d_out head
    gemm_kernel<1><<<dim3(64, 16, 1), 256, 0, stream>>>(comb, Wo, nullptr, nullptr,
                                                        out, nullptr, nullptr);
}

// Round 2
// 821.390 us; speedup vs baseline: 1.5330x; 1.5330x over previous
//
#include <hip/hip_runtime.h>
#include <hip/hip_bf16.h>
#include <math.h>

#define DIM 1024
#define NH 16
#define HD 64
#define NB 2
#define SEQ 2048

typedef short short8 __attribute__((ext_vector_type(8)));
typedef float f32x4 __attribute__((ext_vector_type(4)));

struct WTrue  { static constexpr bool v = true;  };
struct WFalse { static constexpr bool v = false; };

__device__ __forceinline__ float quad_sum(float x) {
    int y = __builtin_amdgcn_mov_dpp(__float_as_int(x), 0xB1, 0xF, 0xF, true); // xor 1
    x += __int_as_float(y);
    y = __builtin_amdgcn_mov_dpp(__float_as_int(x), 0x4E, 0xF, 0xF, true);     // xor 2
    x += __int_as_float(y);
    return x;
}

__device__ __forceinline__ unsigned short f2bf(float f) {
    __hip_bfloat16 h = __float2bfloat16(f);
    return __builtin_bit_cast(unsigned short, h);
}

// ---------------------------------------------------------------------------
// bf16-MFMA GEMM: C[m,n] = sum_k X[m,k] * W[n,k]
// 128x128 tile, BK=64, 256 thr (4 waves, 2x2 of 64x64), reg-staged fp32->bf16
// into XOR-swizzled LDS; mfma_f32_16x16x32_bf16; C/D: col=lane&15,
// row=(lane>>4)*4+reg (m89-verified).
// MODE 0: z selects (W0->O0 etc), head-split out [b,h,s,hd]. MODE 1: [b,s,e].
// ---------------------------------------------------------------------------
template<int MODE>
__global__ __launch_bounds__(256)
void gemm_bf16(const float* __restrict__ X,
               const float* __restrict__ W0, const float* __restrict__ W1,
               const float* __restrict__ W2,
               float* __restrict__ O0, float* __restrict__ O1,
               float* __restrict__ O2)
{
    __shared__ unsigned short As[128 * 64];
    __shared__ unsigned short Bs[128 * 64];

    const float* W; float* O;
    if (MODE == 0) {
        const int z = blockIdx.z;
        W = (z == 0) ? W0 : (z == 1) ? W1 : W2;
        O = (z == 0) ? O0 : (z == 1) ? O1 : O2;
    } else { W = W0; O = O0; }

    const int t    = threadIdx.x;
    const int lane = t & 63;
    const int wave = t >> 6;
    const int wm = wave >> 1, wn = wave & 1;
    const int lr = lane & 15, kg = lane >> 4;
    const int m_base = blockIdx.x * 128;
    const int n_base = blockIdx.y * 128;

    // staging: thread owns row srow, k-halfrange skb..skb+31 of the BK=64 tile
    const int srow = t >> 1;
    const int skb  = (t & 1) * 32;
    const float* Xp = X + (size_t)(m_base + srow) * DIM + skb;
    const float* Wp = W + (size_t)(n_base + srow) * DIM + skb;
    const int wbase = srow * 64;
    const int wswz  = (srow & 7) << 3;   // XOR swizzle in ushort units (16B granules)

    f32x4 acc[4][4];
    #pragma unroll
    for (int i = 0; i < 4; ++i)
        #pragma unroll
        for (int j = 0; j < 4; ++j) {
            f32x4 z = {0.f, 0.f, 0.f, 0.f};
            acc[i][j] = z;
        }

    for (int k0 = 0; k0 < DIM; k0 += 64) {
        float4 ax[8], bx[8];
        #pragma unroll
        for (int g = 0; g < 8; ++g) {
            ax[g] = *(const float4*)(Xp + k0 + g * 4);
            bx[g] = *(const float4*)(Wp + k0 + g * 4);
        }
        __syncthreads();
        #pragma unroll
        for (int g = 0; g < 4; ++g) {
            float fa[8], fb[8];
            *(float4*)&fa[0] = ax[2*g]; *(float4*)&fa[4] = ax[2*g+1];
            *(float4*)&fb[0] = bx[2*g]; *(float4*)&fb[4] = bx[2*g+1];
            short8 pa, pb;
            #pragma unroll
            for (int i = 0; i < 8; ++i) {
                pa[i] = (short)f2bf(fa[i]);
                pb[i] = (short)f2bf(fb[i]);
            }
            const int idx = wbase + ((skb + 8 * g) ^ wswz);
            *(short8*)&As[idx] = pa;
            *(short8*)&Bs[idx] = pb;
        }
        __syncthreads();

        #pragma unroll
        for (int kh = 0; kh < 2; ++kh) {
            short8 afrag[4], bfrag[4];
            #pragma unroll
            for (int fm = 0; fm < 4; ++fm) {
                const int r = wm * 64 + fm * 16 + lr;
                const int idx = r * 64 + (((kh * 32) + kg * 8) ^ ((r & 7) << 3));
                afrag[fm] = *(const short8*)&As[idx];
            }
            #pragma unroll
            for (int fn = 0; fn < 4; ++fn) {
                const int r = wn * 64 + fn * 16 + lr;
                const int idx = r * 64 + (((kh * 32) + kg * 8) ^ ((r & 7) << 3));
                bfrag[fn] = *(const short8*)&Bs[idx];
            }
            #pragma unroll
            for (int fm = 0; fm < 4; ++fm)
                #pragma unroll
                for (int fn = 0; fn < 4; ++fn)
                    acc[fm][fn] = __builtin_amdgcn_mfma_f32_16x16x32_bf16(
                        afrag[fm], bfrag[fn], acc[fm][fn], 0, 0, 0);
        }
    }

    #pragma unroll
    for (int fm = 0; fm < 4; ++fm) {
        const int mrow0 = m_base + wm * 64 + fm * 16 + kg * 4;
        #pragma unroll
        for (int i = 0; i < 4; ++i) {
            const int m = mrow0 + i;
            const int b = m >> 11;
            const int s = m & (SEQ - 1);
            #pragma unroll
            for (int fn = 0; fn < 4; ++fn) {
                const int n = n_base + wn * 64 + fn * 16 + lr;
                const float val = acc[fm][fn][i];
                if (MODE == 0)
                    O[(((size_t)b * NH + (n >> 6)) * SEQ + s) * HD + (n & 63)] = val;
                else
                    O[((size_t)b * SEQ + s) * DIM + n] = val;
            }
        }
    }
}

// ---------------------------------------------------------------------------
// Attention + memory-read + gated combine, balanced q-tile pairing.
// Block (p,h,b), 512 thr: q-tiles qa=p (light) and qb=15-p (heavy) processed
// concurrently; thread owns rowA (from qa) and rowB (from qb), sharing K/V
// LDS reads. Uniform per-thread work (34 tile-units) and <=32 staged tiles.
// ---------------------------------------------------------------------------
__global__ __launch_bounds__(512)
void attn_kernel(const float* __restrict__ q,
                 const float* __restrict__ k,
                 const float* __restrict__ v,
                 const float* __restrict__ memv,
                 const float* __restrict__ normv,
                 const float* __restrict__ gatev,
                 float* __restrict__ combined)
{
    __shared__ float Ks[64][68];
    __shared__ float Vs[64][68];
    __shared__ float Ms[64][68];
    __shared__ float norm_s[64];

    const int p = blockIdx.x;      // 0..7
    const int h = blockIdx.y;
    const int b = blockIdx.z;
    const int qa = p, qb = 15 - p;
    const int na = 2 * qa + 2, nb = 2 * qb + 2;   // na <= nb

    const int t  = threadIdx.x;
    const int c  = t & 3;
    const int rr = t >> 2;         // 0..127
    const int d0 = c << 4;

    const size_t bh = (size_t)b * NH + h;
    const float* qp = q + bh * SEQ * HD;
    const float* kp = k + bh * SEQ * HD;
    const float* vp = v + bh * SEQ * HD;

    const int rowA = qa * 128 + rr;
    const int rowB = qb * 128 + rr;

    {
        const float* Mb = memv + bh * HD * HD;
        #pragma unroll
        for (int u = 0; u < 2; ++u) {
            const int f  = t + (u << 9);
            const int r_ = f >> 4, c4 = (f & 15) << 2;
            *(float4*)&Ms[r_][c4] = *(const float4*)(Mb + r_ * HD + c4);
        }
        if (t < 64) norm_s[t] = normv[bh * HD + t];
    }

    float qA[16], qB[16];
    #pragma unroll
    for (int u = 0; u < 4; ++u) {
        float4 xa = *(const float4*)(qp + (size_t)rowA * HD + d0 + (u << 2));
        float4 xb = *(const float4*)(qp + (size_t)rowB * HD + d0 + (u << 2));
        qA[4*u+0] = xa.x; qA[4*u+1] = xa.y; qA[4*u+2] = xa.z; qA[4*u+3] = xa.w;
        qB[4*u+0] = xb.x; qB[4*u+1] = xb.y; qB[4*u+2] = xb.z; qB[4*u+3] = xb.w;
    }

    float oA[16] = {}, oB[16] = {};
    float mA = -1e30f, mB = -1e30f, lA = 0.f, lB = 0.f;

    auto tile = [&](int kt, auto tag) {
        constexpr bool WA = decltype(tag)::v;
        __syncthreads();
        #pragma unroll
        for (int u = 0; u < 2; ++u) {
            const int f  = t + (u << 9);
            const int r_ = f >> 4, c4 = (f & 15) << 2;
            *(float4*)&Ks[r_][c4] = *(const float4*)(kp + ((size_t)(kt * 64 + r_)) * HD + c4);
            *(float4*)&Vs[r_][c4] = *(const float4*)(vp + ((size_t)(kt * 64 + r_)) * HD + c4);
        }
        __syncthreads();

        for (int ch = 0; ch < 2; ++ch) {
            float scB[32], scA[32];
            float cmB = -1e30f, cmA = -1e30f;
            #pragma unroll
            for (int j = 0; j < 32; ++j) {
                const int jj = (ch << 5) + j;
                float fB = 0.f, fA = 0.f;
                #pragma unroll
                for (int u = 0; u < 4; ++u) {
                    float4 kv = *(const float4*)&Ks[jj][d0 + (u << 2)];
                    fB = fmaf(qB[4*u+0], kv.x, fB);
                    fB = fmaf(qB[4*u+1], kv.y, fB);
                    fB = fmaf(qB[4*u+2], kv.z, fB);
                    fB = fmaf(qB[4*u+3], kv.w, fB);
                    if constexpr (WA) {
                        fA = fmaf(qA[4*u+0], kv.x, fA);
                        fA = fmaf(qA[4*u+1], kv.y, fA);
                        fA = fmaf(qA[4*u+2], kv.z, fA);
                        fA = fmaf(qA[4*u+3], kv.w, fA);
                    }
                }
                const int kgl = kt * 64 + jj;
                fB = quad_sum(fB) * 0.125f;
                fB = (kgl <= rowB) ? fB : -1e30f;
                scB[j] = fB; cmB = fmaxf(cmB, fB);
                if constexpr (WA) {
                    fA = quad_sum(fA) * 0.125f;
                    fA = (kgl <= rowA) ? fA : -1e30f;
                    scA[j] = fA; cmA = fmaxf(cmA, fA);
                }
            }
            const float mnB = fmaxf(mB, cmB);
            const float corB = __expf(mB - mnB);
            lB *= corB; mB = mnB;
            #pragma unroll
            for (int i = 0; i < 16; ++i) oB[i] *= corB;
            if constexpr (WA) {
                const float mnA = fmaxf(mA, cmA);
                const float corA = __expf(mA - mnA);
                lA *= corA; mA = mnA;
                #pragma unroll
                for (int i = 0; i < 16; ++i) oA[i] *= corA;
            }
            #pragma unroll
            for (int j = 0; j < 32; ++j) {
                const int jj = (ch << 5) + j;
                const float pB = __expf(scB[j] - mB); lB += pB;
                float pA = 0.f;
                if constexpr (WA) { pA = __expf(scA[j] - mA); lA += pA; }
                #pragma unroll
                for (int u = 0; u < 4; ++u) {
                    float4 vv = *(const float4*)&Vs[jj][d0 + (u << 2)];
                    oB[4*u+0] = fmaf(pB, vv.x, oB[4*u+0]);
                    oB[4*u+1] = fmaf(pB, vv.y, oB[4*u+1]);
                    oB[4*u+2] = fmaf(pB, vv.z, oB[4*u+2]);
                    oB[4*u+3] = fmaf(pB, vv.w, oB[4*u+3]);
                    if constexpr (WA) {
                        oA[4*u+0] = fmaf(pA, vv.x, oA[4*u+0]);
                        oA[4*u+1] = fmaf(pA, vv.y, oA[4*u+1]);
                        oA[4*u+2] = fmaf(pA, vv.z, oA[4*u+2]);
                        oA[4*u+3] = fmaf(pA, vv.w, oA[4*u+3]);
                    }
                }
            }
        }
    };

    for (int kt = 0; kt < na; ++kt) tile(kt, WTrue{});
    for (int kt = na; kt < nb; ++kt) tile(kt, WFalse{});

    const float g  = 1.f / (1.f + __expf(-gatev[h]));
    const float og = 1.f - g;
    float* rowbuf = (rr < 64) ? &Ks[rr][0] : &Vs[rr - 64][0];

    // ---- epilogue pass A ----
    {
        const float invl = 1.f / lA;
        __syncthreads();
        #pragma unroll
        for (int i = 0; i < 16; ++i) {
            const float x = qA[i];
            rowbuf[d0 + i] = (x > 0.f) ? (x + 1.f) : __expf(x);
        }
        __syncthreads();
        float ma[16] = {}; float nr = 0.f;
        for (int d = 0; d < 64; ++d) {
            const float qv = rowbuf[d];
            nr = fmaf(qv, norm_s[d], nr);
            #pragma unroll
            for (int u = 0; u < 4; ++u) {
                float4 mv = *(const float4*)&Ms[d][d0 + (u << 2)];
                ma[4*u+0] = fmaf(qv, mv.x, ma[4*u+0]);
                ma[4*u+1] = fmaf(qv, mv.y, ma[4*u+1]);
                ma[4*u+2] = fmaf(qv, mv.z, ma[4*u+2]);
                ma[4*u+3] = fmaf(qv, mv.w, ma[4*u+3]);
            }
        }
        const float invn = 1.f / (nr + 1e-6f);
        float* cw = combined + ((size_t)b * SEQ + rowA) * DIM + h * HD + d0;
        #pragma unroll
        for (int u = 0; u < 4; ++u) {
            float4 w;
            w.x = g * (ma[4*u+0] * invn) + og * (oA[4*u+0] * invl);
            w.y = g * (ma[4*u+1] * invn) + og * (oA[4*u+1] * invl);
            w.z = g * (ma[4*u+2] * invn) + og * (oA[4*u+2] * invl);
            w.w = g * (ma[4*u+3] * invn) + og * (oA[4*u+3] * invl);
            *(float4*)(cw + (u << 2)) = w;
        }
    }
    // ---- epilogue pass B ----
    {
        const float invl = 1.f / lB;
        __syncthreads();
        #pragma unroll
        for (int i = 0; i < 16; ++i) {
            const float x = qB[i];
            rowbuf[d0 + i] = (x > 0.f) ? (x + 1.f) : __expf(x);
        }
        __syncthreads();
        float ma[16] = {}; float nr = 0.f;
        for (int d = 0; d < 64; ++d) {
            const float qv = rowbuf[d];
            nr = fmaf(qv, norm_s[d], nr);
            #pragma unroll
            for (int u = 0; u < 4; ++u) {
                float4 mv = *(const float4*)&Ms[d][d0 + (u << 2)];
                ma[4*u+0] = fmaf(qv, mv.x, ma[4*u+0]);
                ma[4*u+1] = fmaf(qv, mv.y, ma[4*u+1]);
                ma[4*u+2] = fmaf(qv, mv.z, ma[4*u+2]);
                ma[4*u+3] = fmaf(qv, mv.w, ma[4*u+3]);
            }
        }
        const float invn = 1.f / (nr + 1e-6f);
        float* cw = combined + ((size_t)b * SEQ + rowB) * DIM + h * HD + d0;
        #pragma unroll
        for (int u = 0; u < 4; ++u) {
            float4 w;
            w.x = g * (ma[4*u+0] * invn) + og * (oB[4*u+0] * invl);
            w.y = g * (ma[4*u+1] * invn) + og * (oB[4*u+1] * invl);
            w.z = g * (ma[4*u+2] * invn) + og * (oB[4*u+2] * invl);
            w.w = g * (ma[4*u+3] * invn) + og * (oB[4*u+3] * invl);
            *(float4*)(cw + (u << 2)) = w;
        }
    }
}

// ---------------------------------------------------------------------------
// Memory write: new_mem[bh,d,e] = mem + sum_s (elu(k)+1)[s,d] * v[s,e]
// ---------------------------------------------------------------------------
__global__ __launch_bounds__(1024)
void memwrite_kernel(const float* __restrict__ k,
                     const float* __restrict__ v,
                     const float* __restrict__ memv,
                     const float* __restrict__ normv,
                     float* __restrict__ new_mem,
                     float* __restrict__ new_norm)
{
    __shared__ float Ks[64][68];
    __shared__ float Vs[64][68];

    const int bh = blockIdx.x;
    const int t  = threadIdx.x;
    const int dr = t >> 4;
    const int c  = t & 15;
    const int e0 = c << 2;

    const float* kb = k + (size_t)bh * SEQ * HD;
    const float* vb = v + (size_t)bh * SEQ * HD;

    float acc[4] = {};
    float nacc = 0.f;

    for (int st = 0; st < SEQ / 64; ++st) {
        __syncthreads();
        {
            const int r_ = t >> 4;
            const int c4 = (t & 15) << 2;
            *(float4*)&Ks[r_][c4] = *(const float4*)(kb + ((size_t)(st * 64 + r_)) * HD + c4);
            *(float4*)&Vs[r_][c4] = *(const float4*)(vb + ((size_t)(st * 64 + r_)) * HD + c4);
        }
        __syncthreads();
        #pragma unroll 8
        for (int ss = 0; ss < 64; ++ss) {
            const float kraw = Ks[ss][dr];
            const float km = (kraw > 0.f) ? (kraw + 1.f) : __expf(kraw);
            nacc += km;
            float4 vv = *(const float4*)&Vs[ss][e0];
            acc[0] = fmaf(km, vv.x, acc[0]);
            acc[1] = fmaf(km, vv.y, acc[1]);
            acc[2] = fmaf(km, vv.z, acc[2]);
            acc[3] = fmaf(km, vv.w, acc[3]);
        }
    }

    const size_t off = ((size_t)bh * HD + dr) * HD + e0;
    float4 mold = *(const float4*)(memv + off);
    *(float4*)(new_mem + off) = make_float4(mold.x + acc[0], mold.y + acc[1],
                                            mold.z + acc[2], mold.w + acc[3]);
    if (c == 0) new_norm[(size_t)bh * HD + dr] = normv[(size_t)bh * HD + dr] + nacc;
}

// ---------------------------------------------------------------------------
extern "C" void kernel_launch(void* const* d_in, const int* in_sizes, int n_in,
                              void* d_out, int out_size, void* d_ws, size_t ws_size,
                              hipStream_t stream)
{
    const float* x     = (const float*)d_in[0];
    const float* memv  = (const float*)d_in[1];
    const float* normv = (const float*)d_in[2];
    const float* Wq    = (const float*)d_in[3];
    const float* Wk    = (const float*)d_in[4];
    const float* Wv    = (const float*)d_in[5];
    const float* Wo    = (const float*)d_in[6];
    const float* gate  = (const float*)d_in[7];
    float* out = (float*)d_out;

    const size_t NQ = (size_t)NB * NH * SEQ * HD;
    float* qbuf = (float*)d_ws;
    float* kbuf = qbuf + NQ;
    float* vbuf = kbuf + NQ;
    float* comb = vbuf + NQ;

    float* new_mem  = out + (size_t)NB * SEQ * DIM;
    float* new_norm = new_mem + (size_t)NB * NH * HD * HD;

    gemm_bf16<0><<<dim3(32, 8, 3), 256, 0, stream>>>(x, Wq, Wk, Wv, qbuf, kbuf, vbuf);
    attn_kernel<<<dim3(8, 16, 2), 512, 0, stream>>>(qbuf, kbuf, vbuf, memv, normv, gate, comb);
    memwrite_kernel<<<dim3(32), 1024, 0, stream>>>(kbuf, vbuf, memv, normv, new_mem, new_norm);
    gemm_bf16<1><<<dim3(32, 8, 1), 256, 0, stream>>>(comb, Wo, nullptr, nullptr,
                                                     out, nullptr, nullptr);
}

// Round 3
// 308.768 us; speedup vs baseline: 4.0780x; 2.6602x over previous
//
#include <hip/hip_runtime.h>
#include <hip/hip_bf16.h>
#include <math.h>
#include <type_traits>

#define DIM 1024
#define NH 16
#define HD 64
#define NB 2
#define SEQ 2048

typedef short short8 __attribute__((ext_vector_type(8)));
typedef float f32x4 __attribute__((ext_vector_type(4)));
typedef unsigned short ushort4v __attribute__((ext_vector_type(4)));

#if __has_builtin(__builtin_amdgcn_exp2f)
#define EXP2(x) __builtin_amdgcn_exp2f(x)
#else
#define EXP2(x) exp2f(x)
#endif
#define LOG2E 1.44269504f

__device__ __forceinline__ unsigned short f2bf(float f) {
    __hip_bfloat16 h = __float2bfloat16(f);
    return __builtin_bit_cast(unsigned short, h);
}

// ---------------------------------------------------------------------------
// bf16-MFMA GEMM: C[m,n] = sum_k X[m,k] * W[n,k]  (unchanged from round 2)
// ---------------------------------------------------------------------------
template<int MODE>
__global__ __launch_bounds__(256)
void gemm_bf16(const float* __restrict__ X,
               const float* __restrict__ W0, const float* __restrict__ W1,
               const float* __restrict__ W2,
               float* __restrict__ O0, float* __restrict__ O1,
               float* __restrict__ O2)
{
    __shared__ unsigned short As[128 * 64];
    __shared__ unsigned short Bs[128 * 64];

    const float* W; float* O;
    if (MODE == 0) {
        const int z = blockIdx.z;
        W = (z == 0) ? W0 : (z == 1) ? W1 : W2;
        O = (z == 0) ? O0 : (z == 1) ? O1 : O2;
    } else { W = W0; O = O0; }

    const int t    = threadIdx.x;
    const int lane = t & 63;
    const int wave = t >> 6;
    const int wm = wave >> 1, wn = wave & 1;
    const int lr = lane & 15, kg = lane >> 4;
    const int m_base = blockIdx.x * 128;
    const int n_base = blockIdx.y * 128;

    const int srow = t >> 1;
    const int skb  = (t & 1) * 32;
    const float* Xp = X + (size_t)(m_base + srow) * DIM + skb;
    const float* Wp = W + (size_t)(n_base + srow) * DIM + skb;
    const int wbase = srow * 64;
    const int wswz  = (srow & 7) << 3;

    f32x4 acc[4][4];
    #pragma unroll
    for (int i = 0; i < 4; ++i)
        #pragma unroll
        for (int j = 0; j < 4; ++j) {
            f32x4 z = {0.f, 0.f, 0.f, 0.f};
            acc[i][j] = z;
        }

    for (int k0 = 0; k0 < DIM; k0 += 64) {
        float4 ax[8], bx[8];
        #pragma unroll
        for (int g = 0; g < 8; ++g) {
            ax[g] = *(const float4*)(Xp + k0 + g * 4);
            bx[g] = *(const float4*)(Wp + k0 + g * 4);
        }
        __syncthreads();
        #pragma unroll
        for (int g = 0; g < 4; ++g) {
            float fa[8], fb[8];
            *(float4*)&fa[0] = ax[2*g]; *(float4*)&fa[4] = ax[2*g+1];
            *(float4*)&fb[0] = bx[2*g]; *(float4*)&fb[4] = bx[2*g+1];
            short8 pa, pb;
            #pragma unroll
            for (int i = 0; i < 8; ++i) {
                pa[i] = (short)f2bf(fa[i]);
                pb[i] = (short)f2bf(fb[i]);
            }
            const int idx = wbase + ((skb + 8 * g) ^ wswz);
            *(short8*)&As[idx] = pa;
            *(short8*)&Bs[idx] = pb;
        }
        __syncthreads();

        #pragma unroll
        for (int kh = 0; kh < 2; ++kh) {
            short8 afrag[4], bfrag[4];
            #pragma unroll
            for (int fm = 0; fm < 4; ++fm) {
                const int r = wm * 64 + fm * 16 + lr;
                const int idx = r * 64 + (((kh * 32) + kg * 8) ^ ((r & 7) << 3));
                afrag[fm] = *(const short8*)&As[idx];
            }
            #pragma unroll
            for (int fn = 0; fn < 4; ++fn) {
                const int r = wn * 64 + fn * 16 + lr;
                const int idx = r * 64 + (((kh * 32) + kg * 8) ^ ((r & 7) << 3));
                bfrag[fn] = *(const short8*)&Bs[idx];
            }
            #pragma unroll
            for (int fm = 0; fm < 4; ++fm)
                #pragma unroll
                for (int fn = 0; fn < 4; ++fn)
                    acc[fm][fn] = __builtin_amdgcn_mfma_f32_16x16x32_bf16(
                        afrag[fm], bfrag[fn], acc[fm][fn], 0, 0, 0);
        }
    }

    #pragma unroll
    for (int fm = 0; fm < 4; ++fm) {
        const int mrow0 = m_base + wm * 64 + fm * 16 + kg * 4;
        #pragma unroll
        for (int i = 0; i < 4; ++i) {
            const int m = mrow0 + i;
            const int b = m >> 11;
            const int s = m & (SEQ - 1);
            #pragma unroll
            for (int fn = 0; fn < 4; ++fn) {
                const int n = n_base + wn * 64 + fn * 16 + lr;
                const float val = acc[fm][fn][i];
                if (MODE == 0)
                    O[(((size_t)b * NH + (n >> 6)) * SEQ + s) * HD + (n & 63)] = val;
                else
                    O[((size_t)b * SEQ + s) * DIM + n] = val;
            }
        }
    }
}

// ---------------------------------------------------------------------------
// MFMA flash attention + memory read + gated combine.
// Block (p,h,b), 256 thr / 4 waves. Paired q-tiles qa=p (fm0), qb=31-p (fm1),
// 64 rows each; wave w owns rows [qX*64+w*16, +16). KV tiles of 64.
// K row-major bf16 LDS; V,M transposed bf16 LDS; P via per-wave LDS.
// mfma_f32_16x16x32_bf16: A/B row=lane&15, k=(lane>>4)*8+i;
// C/D row=(lane>>4)*4+reg, col=lane&15 (verified by gemm_bf16 above).
// ---------------------------------------------------------------------------
__global__ __launch_bounds__(256)
void attn_mfma(const float* __restrict__ q,
               const float* __restrict__ k,
               const float* __restrict__ v,
               const float* __restrict__ memv,
               const float* __restrict__ normv,
               const float* __restrict__ gatev,
               float* __restrict__ comb)
{
    __shared__ unsigned short Ks[64 * 72];
    __shared__ unsigned short Vt[64 * 72];
    __shared__ unsigned short Mt[64 * 72];
    __shared__ unsigned short Ps[4 * 32 * 72];
    __shared__ float norm_s[64];

    const int p = blockIdx.x;      // 0..15
    const int h = blockIdx.y;
    const int b = blockIdx.z;
    const int qa = p, qb = 31 - p;
    const int na = qa + 1, nb = qb + 1;

    const int t    = threadIdx.x;
    const int lane = t & 63;
    const int w    = t >> 6;
    const int lr   = lane & 15;
    const int kg   = lane >> 4;

    const size_t bh = (size_t)b * NH + h;
    const float* qp = q + bh * SEQ * HD;
    const float* kp = k + bh * SEQ * HD;
    const float* vp = v + bh * SEQ * HD;

    // ---- stage Mt (transposed M) + norm vector ----
    {
        const float* Mb = memv + bh * HD * HD;
        #pragma unroll
        for (int u = 0; u < 16; ++u) {
            const int flat = t + (u << 8);          // 0..4095, = d*64 + e
            Mt[(flat & 63) * 72 + (flat >> 6)] = f2bf(Mb[flat]);
        }
        if (t < 64) norm_s[t] = normv[bh * HD + t];
    }
    __syncthreads();

    // ---- Q prologue: A-frags for attention (x0.125) and memory read (elu+1) ----
    const int rbase0 = qa * 64 + w * 16;
    const int rbase1 = qb * 64 + w * 16;
    short8 qatt[2][2], qmem[2][2];
    float nrrow[2];
    #pragma unroll
    for (int fm = 0; fm < 2; ++fm) {
        const int rb = fm ? rbase1 : rbase0;
        const float* qrow = qp + (size_t)(rb + lr) * HD;
        float nr = 0.f;
        #pragma unroll
        for (int kk = 0; kk < 2; ++kk) {
            const int dbase = kk * 32 + kg * 8;
            float4 a0 = *(const float4*)(qrow + dbase);
            float4 a1 = *(const float4*)(qrow + dbase + 4);
            float vals[8];
            *(float4*)&vals[0] = a0; *(float4*)&vals[4] = a1;
            short8 sa, sm;
            #pragma unroll
            for (int i = 0; i < 8; ++i) {
                const float x = vals[i];
                sa[i] = (short)f2bf(x * 0.125f);
                const float e = (x > 0.f) ? (x + 1.f) : __expf(x);
                sm[i] = (short)f2bf(e);
                nr = fmaf(e, norm_s[dbase + i], nr);
            }
            qatt[fm][kk] = sa;
            qmem[fm][kk] = sm;
        }
        nr += __shfl_xor(nr, 16);
        nr += __shfl_xor(nr, 32);
        nrrow[fm] = nr;   // full row-sum for row rb+lr
    }

    f32x4 oacc[2][4];
    #pragma unroll
    for (int fm = 0; fm < 2; ++fm)
        #pragma unroll
        for (int fn = 0; fn < 4; ++fn) {
            f32x4 z = {0.f, 0.f, 0.f, 0.f};
            oacc[fm][fn] = z;
        }
    float mrow[2][4], lrow[2][4];
    #pragma unroll
    for (int fm = 0; fm < 2; ++fm)
        #pragma unroll
        for (int r = 0; r < 4; ++r) { mrow[fm][r] = -1e30f; lrow[fm][r] = 0.f; }

    const int pbase = w * (32 * 72);

    // ---- main KV loop ----
    for (int kt = 0; kt < nb; ++kt) {
        __syncthreads();
        // stage K row-major bf16
        {
            const float4* ksrc = (const float4*)(kp + (size_t)kt * 64 * HD);
            #pragma unroll
            for (int u = 0; u < 4; ++u) {
                const int f4 = t + (u << 8);         // float4 index; row=f4>>4, c4=(f4&15)*4
                float4 kv4 = ksrc[f4];
                ushort4v uv;
                uv[0] = f2bf(kv4.x); uv[1] = f2bf(kv4.y);
                uv[2] = f2bf(kv4.z); uv[3] = f2bf(kv4.w);
                *(ushort4v*)&Ks[(f4 >> 4) * 72 + ((f4 & 15) << 2)] = uv;
            }
        }
        // stage V transposed bf16 (linear read, scatter write: 2-way banks = free)
        {
            const float* vsrc = vp + (size_t)kt * 64 * HD;
            #pragma unroll
            for (int u = 0; u < 16; ++u) {
                const int flat = t + (u << 8);       // = krow*64 + d
                Vt[(flat & 63) * 72 + (flat >> 6)] = f2bf(vsrc[flat]);
            }
        }
        __syncthreads();

        const bool doA = (kt < na);

        // K B-frags (shared by both fm)
        short8 kf[4][2];
        #pragma unroll
        for (int fn = 0; fn < 4; ++fn)
            #pragma unroll
            for (int kk = 0; kk < 2; ++kk)
                kf[fn][kk] = *(const short8*)&Ks[(fn * 16 + lr) * 72 + kk * 32 + kg * 8];

        // QK^T + online softmax + P-store, per active fm (compile-time fm)
        auto qk_fm = [&](auto FM) {
            constexpr int fm = FM.value;
            const int rb = fm ? rbase1 : rbase0;
            f32x4 S[4];
            #pragma unroll
            for (int fn = 0; fn < 4; ++fn) {
                f32x4 z = {0.f, 0.f, 0.f, 0.f};
                S[fn] = z;
            }
            #pragma unroll
            for (int fn = 0; fn < 4; ++fn)
                #pragma unroll
                for (int kk = 0; kk < 2; ++kk)
                    S[fn] = __builtin_amdgcn_mfma_f32_16x16x32_bf16(
                        qatt[fm][kk], kf[fn][kk], S[fn], 0, 0, 0);

            float sl[4][4];
            float cm[4] = {-1e30f, -1e30f, -1e30f, -1e30f};
            #pragma unroll
            for (int fn = 0; fn < 4; ++fn) {
                const int kgl = kt * 64 + fn * 16 + lr;
                #pragma unroll
                for (int r = 0; r < 4; ++r) {
                    float s = S[fn][r] * LOG2E;
                    const int qg = rb + kg * 4 + r;
                    if (kgl > qg) s = -1e30f;
                    sl[fn][r] = s;
                    cm[r] = fmaxf(cm[r], s);
                }
            }
            #pragma unroll
            for (int r = 0; r < 4; ++r) {
                cm[r] = fmaxf(cm[r], __shfl_xor(cm[r], 1));
                cm[r] = fmaxf(cm[r], __shfl_xor(cm[r], 2));
                cm[r] = fmaxf(cm[r], __shfl_xor(cm[r], 4));
                cm[r] = fmaxf(cm[r], __shfl_xor(cm[r], 8));
                const float mn = fmaxf(mrow[fm][r], cm[r]);
                const float corr = EXP2(mrow[fm][r] - mn);
                mrow[fm][r] = mn;
                lrow[fm][r] *= corr;
                #pragma unroll
                for (int fn = 0; fn < 4; ++fn) oacc[fm][fn][r] *= corr;
            }
            float rs[4] = {0.f, 0.f, 0.f, 0.f};
            #pragma unroll
            for (int fn = 0; fn < 4; ++fn)
                #pragma unroll
                for (int r = 0; r < 4; ++r) {
                    const float pe = EXP2(sl[fn][r] - mrow[fm][r]);
                    rs[r] += pe;
                    Ps[pbase + (fm * 16 + kg * 4 + r) * 72 + fn * 16 + lr] =
                        f2bf(pe);
                }
            #pragma unroll
            for (int r = 0; r < 4; ++r) {
                rs[r] += __shfl_xor(rs[r], 1);
                rs[r] += __shfl_xor(rs[r], 2);
                rs[r] += __shfl_xor(rs[r], 4);
                rs[r] += __shfl_xor(rs[r], 8);
                lrow[fm][r] += rs[r];
            }
        };
        if (doA) qk_fm(std::integral_constant<int, 0>{});
        qk_fm(std::integral_constant<int, 1>{});

        // PV
        short8 vf[4][2];
        #pragma unroll
        for (int fnd = 0; fnd < 4; ++fnd)
            #pragma unroll
            for (int kk = 0; kk < 2; ++kk)
                vf[fnd][kk] = *(const short8*)&Vt[(fnd * 16 + lr) * 72 + kk * 32 + kg * 8];

        auto pv_fm = [&](auto FM) {
            constexpr int fm = FM.value;
            short8 pf[2];
            #pragma unroll
            for (int kk = 0; kk < 2; ++kk)
                pf[kk] = *(const short8*)&Ps[pbase + (fm * 16 + lr) * 72 + kk * 32 + kg * 8];
            #pragma unroll
            for (int fnd = 0; fnd < 4; ++fnd)
                #pragma unroll
                for (int kk = 0; kk < 2; ++kk)
                    oacc[fm][fnd] = __builtin_amdgcn_mfma_f32_16x16x32_bf16(
                        pf[kk], vf[fnd][kk], oacc[fm][fnd], 0, 0, 0);
        };
        if (doA) pv_fm(std::integral_constant<int, 0>{});
        pv_fm(std::integral_constant<int, 1>{});
    }

    // ---- epilogue: memory read via MFMA (same C-layout as oacc) ----
    short8 mf[4][2];
    #pragma unroll
    for (int fn = 0; fn < 4; ++fn)
        #pragma unroll
        for (int kk = 0; kk < 2; ++kk)
            mf[fn][kk] = *(const short8*)&Mt[(fn * 16 + lr) * 72 + kk * 32 + kg * 8];

    f32x4 macc[2][4];
    #pragma unroll
    for (int fm = 0; fm < 2; ++fm)
        #pragma unroll
        for (int fn = 0; fn < 4; ++fn) {
            f32x4 z = {0.f, 0.f, 0.f, 0.f};
            macc[fm][fn] = z;
            #pragma unroll
            for (int kk = 0; kk < 2; ++kk)
                macc[fm][fn] = __builtin_amdgcn_mfma_f32_16x16x32_bf16(
                    qmem[fm][kk], mf[fn][kk], macc[fm][fn], 0, 0, 0);
        }

    const float g  = 1.f / (1.f + __expf(-gatev[h]));
    const float og = 1.f - g;

    #pragma unroll
    for (int fm = 0; fm < 2; ++fm) {
        const int rb = fm ? rbase1 : rbase0;
        #pragma unroll
        for (int r = 0; r < 4; ++r) {
            const int rt  = kg * 4 + r;
            const int src = (lane & 48) | rt;
            const float nrd   = __shfl(nrrow[fm], src);
            const float nrinv = 1.f / (nrd + 1e-6f);
            const float linv  = 1.f / lrow[fm][r];
            const int qg = rb + rt;
            float* crow = comb + ((size_t)b * SEQ + qg) * DIM + h * HD;
            #pragma unroll
            for (int fn = 0; fn < 4; ++fn)
                crow[fn * 16 + lr] =
                    g * (macc[fm][fn][r] * nrinv) + og * (oacc[fm][fn][r] * linv);
        }
    }
}

// ---------------------------------------------------------------------------
// Memory write, chunked: part[bh][ch] = sum over s-chunk of (elu(k)+1) v^T
// ---------------------------------------------------------------------------
__global__ __launch_bounds__(256)
void memwrite_part(const float* __restrict__ k,
                   const float* __restrict__ v,
                   float* __restrict__ part,
                   float* __restrict__ pnorm)
{
    __shared__ float Kel[64][65];
    __shared__ float Vsm[64][65];

    const int ch = blockIdx.x;   // 0..7
    const int bh = blockIdx.y;   // 0..31
    const int t  = threadIdx.x;
    const int dr = t >> 2;       // 0..63
    const int e0 = (t & 3) << 4; // 0,16,32,48

    const float* kb = k + (size_t)bh * SEQ * HD + (size_t)ch * 256 * HD;
    const float* vb = v + (size_t)bh * SEQ * HD + (size_t)ch * 256 * HD;

    float acc[16] = {};
    float nacc = 0.f;

    for (int st = 0; st < 4; ++st) {
        __syncthreads();
        #pragma unroll
        for (int u = 0; u < 4; ++u) {
            const int f4 = t + (u << 8);
            const int r_ = f4 >> 4, c4 = (f4 & 15) << 2;
            float4 kv = *(const float4*)(kb + (size_t)(st * 64 + r_) * HD + c4);
            float4 vv = *(const float4*)(vb + (size_t)(st * 64 + r_) * HD + c4);
            Kel[r_][c4+0] = (kv.x > 0.f) ? kv.x + 1.f : __expf(kv.x);
            Kel[r_][c4+1] = (kv.y > 0.f) ? kv.y + 1.f : __expf(kv.y);
            Kel[r_][c4+2] = (kv.z > 0.f) ? kv.z + 1.f : __expf(kv.z);
            Kel[r_][c4+3] = (kv.w > 0.f) ? kv.w + 1.f : __expf(kv.w);
            *(float4*)&Vsm[r_][c4] = vv;
        }
        __syncthreads();
        #pragma unroll 8
        for (int ss = 0; ss < 64; ++ss) {
            const float km = Kel[ss][dr];
            nacc += km;
            #pragma unroll
            for (int j = 0; j < 4; ++j) {
                float4 vv = *(const float4*)&Vsm[ss][e0 + j * 4];
                acc[4*j+0] = fmaf(km, vv.x, acc[4*j+0]);
                acc[4*j+1] = fmaf(km, vv.y, acc[4*j+1]);
                acc[4*j+2] = fmaf(km, vv.z, acc[4*j+2]);
                acc[4*j+3] = fmaf(km, vv.w, acc[4*j+3]);
            }
        }
    }

    float* po = part + (((size_t)bh * 8 + ch) * 64 + dr) * 64 + e0;
    #pragma unroll
    for (int j = 0; j < 4; ++j)
        *(float4*)(po + j * 4) = *(float4*)&acc[4*j];
    if ((t & 3) == 0) pnorm[((size_t)bh * 8 + ch) * 64 + dr] = nacc;
}

__global__ __launch_bounds__(256)
void memwrite_reduce(const float* __restrict__ part,
                     const float* __restrict__ pnorm,
                     const float* __restrict__ memv,
                     const float* __restrict__ normv,
                     float* __restrict__ new_mem,
                     float* __restrict__ new_norm)
{
    const int bh = blockIdx.x;
    const int t  = threadIdx.x;
    #pragma unroll
    for (int u = 0; u < 16; ++u) {
        const int fl = t + (u << 8);   // 0..4095
        float s = memv[(size_t)bh * 4096 + fl];
        #pragma unroll
        for (int ch = 0; ch < 8; ++ch)
            s += part[((size_t)bh * 8 + ch) * 4096 + fl];
        new_mem[(size_t)bh * 4096 + fl] = s;
    }
    if (t < 64) {
        float s = normv[(size_t)bh * 64 + t];
        #pragma unroll
        for (int ch = 0; ch < 8; ++ch)
            s += pnorm[((size_t)bh * 8 + ch) * 64 + t];
        new_norm[(size_t)bh * 64 + t] = s;
    }
}

// ---------------------------------------------------------------------------
extern "C" void kernel_launch(void* const* d_in, const int* in_sizes, int n_in,
                              void* d_out, int out_size, void* d_ws, size_t ws_size,
                              hipStream_t stream)
{
    const float* x     = (const float*)d_in[0];
    const float* memv  = (const float*)d_in[1];
    const float* normv = (const float*)d_in[2];
    const float* Wq    = (const float*)d_in[3];
    const float* Wk    = (const float*)d_in[4];
    const float* Wv    = (const float*)d_in[5];
    const float* Wo    = (const float*)d_in[6];
    const float* gate  = (const float*)d_in[7];
    float* out = (float*)d_out;

    const size_t NQ = (size_t)NB * NH * SEQ * HD;
    float* qbuf = (float*)d_ws;
    float* kbuf = qbuf + NQ;
    float* vbuf = kbuf + NQ;
    float* comb = vbuf + NQ;
    // part/pnorm alias qbuf: used only after attn_mfma has consumed q
    float* part  = qbuf;                       // 32*8*4096 = 1,048,576 floats
    float* pnorm = qbuf + (size_t)32 * 8 * 4096;

    float* new_mem  = out + (size_t)NB * SEQ * DIM;
    float* new_norm = new_mem + (size_t)NB * NH * HD * HD;

    gemm_bf16<0><<<dim3(32, 8, 3), 256, 0, stream>>>(x, Wq, Wk, Wv, qbuf, kbuf, vbuf);
    attn_mfma<<<dim3(16, 16, 2), 256, 0, stream>>>(qbuf, kbuf, vbuf, memv, normv, gate, comb);
    memwrite_part<<<dim3(8, 32), 256, 0, stream>>>(kbuf, vbuf, part, pnorm);
    memwrite_reduce<<<dim3(32), 256, 0, stream>>>(part, pnorm, memv, normv, new_mem, new_norm);
    gemm_bf16<1><<<dim3(32, 8, 1), 256, 0, stream>>>(comb, Wo, nullptr, nullptr,
                                                     out, nullptr, nullptr);
}

// Round 4
// 271.125 us; speedup vs baseline: 4.6442x; 1.1388x over previous
//
#include <hip/hip_runtime.h>
#include <hip/hip_bf16.h>
#include <math.h>
#include <type_traits>

#define DIM 1024
#define NH 16
#define HD 64
#define NB 2
#define SEQ 2048

typedef unsigned short u16;
typedef short short8 __attribute__((ext_vector_type(8)));
typedef unsigned short u16x8 __attribute__((ext_vector_type(8)));
typedef float f32x4 __attribute__((ext_vector_type(4)));

#define LOG2E 1.44269504f

__device__ __forceinline__ u16 f2bf(float f) {
    __hip_bfloat16 h = __float2bfloat16(f);
    return __builtin_bit_cast(u16, h);
}
__device__ __forceinline__ float bf2f(u16 u) {
    return __uint_as_float(((unsigned)u) << 16);
}

// global -> LDS direct async copy, 16B per lane. LDS dest must be linear
// (wave base + lane*16); swizzling is done on the SOURCE address (m173).
__device__ __forceinline__ void gload_lds16(const u16* g, u16* l) {
    __builtin_amdgcn_global_load_lds(
        (const __attribute__((address_space(1))) unsigned int*)g,
        (__attribute__((address_space(3))) unsigned int*)l, 16, 0, 0);
}

// ---------------------------------------------------------------------------
// fp32 -> bf16 conversion pass: y=0: x (4.19M), y=1..4: Wq/Wk/Wv/Wo (1M each)
// ---------------------------------------------------------------------------
__global__ __launch_bounds__(256)
void conv_bf16(const float* __restrict__ x,
               const float* __restrict__ wq, const float* __restrict__ wk,
               const float* __restrict__ wv, const float* __restrict__ wo,
               u16* __restrict__ xbf, u16* __restrict__ wbf)
{
    const int y = blockIdx.y;
    const float* src; u16* dst; int n;
    if (y == 0)      { src = x;  dst = xbf;              n = 1 << 22; }
    else if (y == 1) { src = wq; dst = wbf;              n = 1 << 20; }
    else if (y == 2) { src = wk; dst = wbf + (1 << 20);  n = 1 << 20; }
    else if (y == 3) { src = wv; dst = wbf + (2 << 20);  n = 1 << 20; }
    else             { src = wo; dst = wbf + (3 << 20);  n = 1 << 20; }
    const int i8 = (blockIdx.x * 256 + threadIdx.x) * 8;
    if (i8 >= n) return;
    float4 a = *(const float4*)(src + i8);
    float4 b = *(const float4*)(src + i8 + 4);
    u16x8 o;
    o[0] = f2bf(a.x); o[1] = f2bf(a.y); o[2] = f2bf(a.z); o[3] = f2bf(a.w);
    o[4] = f2bf(b.x); o[5] = f2bf(b.y); o[6] = f2bf(b.z); o[7] = f2bf(b.w);
    *(u16x8*)(dst + i8) = o;
}

// ---------------------------------------------------------------------------
// bf16 GEMM via global_load_lds (m97 structure): C[m,n] = sum_k X[m,k]*W[n,k]
// Tile MT x 128 (MT = FM*32), BK=64, 256 thr / 4 waves (2x2).
// LDS linear [row][64] bf16; source chunks pre-swizzled: chunk c fetches
// global chunk c ^ (row&7); ds_read at (c ^ (row&7)) recovers chunk c.
// MODE 0: z = blockIdx.z selects W-slice/out-slice; bf16 head-split out.
// MODE 1: fp32 flat out [b,s,e].
// ---------------------------------------------------------------------------
template<int MODE, int FM>
__global__ __launch_bounds__(256)
void gemm_lds(const u16* __restrict__ X, const u16* __restrict__ Wall,
              u16* __restrict__ Obf, float* __restrict__ Of)
{
    constexpr int MT = FM * 32;
    __shared__ u16 As[MT * 64];
    __shared__ u16 Bs[128 * 64];

    const int t    = threadIdx.x;
    const int lane = t & 63;
    const int wave = t >> 6;
    const int wm = wave >> 1, wn = wave & 1;
    const int lr = lane & 15, kg = lane >> 4;
    const int m_base = blockIdx.x * MT;
    const int n_base = blockIdx.y * 128;

    const u16* Xb = X + (size_t)m_base * DIM;
    const u16* Wb = Wall + (MODE == 0 ? ((size_t)blockIdx.z << 20) : (size_t)0)
                         + (size_t)n_base * DIM;

    f32x4 acc[FM][4];
    #pragma unroll
    for (int i = 0; i < FM; ++i)
        #pragma unroll
        for (int j = 0; j < 4; ++j) {
            f32x4 z = {0.f, 0.f, 0.f, 0.f};
            acc[i][j] = z;
        }

    for (int k0 = 0; k0 < DIM; k0 += 64) {
        __syncthreads();
        #pragma unroll
        for (int u = 0; u < FM; ++u) {
            const int cid = (u << 8) + t;          // A chunk id
            const int row = cid >> 3, c16 = cid & 7;
            const int src = c16 ^ (row & 7);
            gload_lds16(Xb + (size_t)row * DIM + k0 + (src << 3), &As[cid << 3]);
        }
        #pragma unroll
        for (int u = 0; u < 4; ++u) {
            const int cid = (u << 8) + t;          // B chunk id
            const int row = cid >> 3, c16 = cid & 7;
            const int src = c16 ^ (row & 7);
            gload_lds16(Wb + (size_t)row * DIM + k0 + (src << 3), &Bs[cid << 3]);
        }
        __syncthreads();

        #pragma unroll
        for (int kh = 0; kh < 2; ++kh) {
            short8 afrag[FM], bfrag[4];
            #pragma unroll
            for (int fm = 0; fm < FM; ++fm) {
                const int r = wm * (FM * 16) + fm * 16 + lr;
                const int c = (kh << 2) + kg;
                afrag[fm] = *(const short8*)&As[r * 64 + (((c) ^ (r & 7)) << 3)];
            }
            #pragma unroll
            for (int fn = 0; fn < 4; ++fn) {
                const int r = wn * 64 + fn * 16 + lr;
                const int c = (kh << 2) + kg;
                bfrag[fn] = *(const short8*)&Bs[r * 64 + (((c) ^ (r & 7)) << 3)];
            }
            #pragma unroll
            for (int fm = 0; fm < FM; ++fm)
                #pragma unroll
                for (int fn = 0; fn < 4; ++fn)
                    acc[fm][fn] = __builtin_amdgcn_mfma_f32_16x16x32_bf16(
                        afrag[fm], bfrag[fn], acc[fm][fn], 0, 0, 0);
        }
    }

    u16* O0 = (MODE == 0) ? Obf + ((size_t)blockIdx.z << 22) : nullptr;
    #pragma unroll
    for (int fm = 0; fm < FM; ++fm) {
        const int mrow0 = m_base + wm * (FM * 16) + fm * 16 + kg * 4;
        #pragma unroll
        for (int i = 0; i < 4; ++i) {
            const int m = mrow0 + i;
            const int b = m >> 11;
            const int s = m & (SEQ - 1);
            #pragma unroll
            for (int fn = 0; fn < 4; ++fn) {
                const int n = n_base + wn * 64 + fn * 16 + lr;
                const float val = acc[fm][fn][i];
                if (MODE == 0)
                    O0[(((size_t)b * NH + (n >> 6)) * SEQ + s) * HD + (n & 63)] =
                        f2bf(val);
                else
                    Of[((size_t)b * SEQ + s) * DIM + n] = val;
            }
        }
    }
}

// ---------------------------------------------------------------------------
// MFMA flash attention + memory read + gated combine (bf16 q/k/v in, bf16 out)
// Block (p,h,b), 256 thr / 4 waves. Paired q-tiles qa=p, qb=31-p, 64 rows each.
// K staged via global_load_lds + source swizzle; V transposed via reg staging;
// P through per-wave swizzled LDS; softmax scale 0.125 folded into logits.
// ---------------------------------------------------------------------------
__global__ __launch_bounds__(256)
void attn_mfma(const u16* __restrict__ q,
               const u16* __restrict__ k,
               const u16* __restrict__ v,
               const float* __restrict__ memv,
               const float* __restrict__ normv,
               const float* __restrict__ gatev,
               u16* __restrict__ comb)
{
    __shared__ u16 Ks[64 * 64];          // swizzled-linear, gload_lds dest
    __shared__ u16 Vt[64 * 72];          // transposed V
    __shared__ u16 Mt[64 * 72];          // transposed memory matrix
    __shared__ u16 Ps[4 * 32 * 64];      // per-wave P, chunk-swizzled
    __shared__ float norm_s[64];

    const int p = blockIdx.x;
    const int h = blockIdx.y;
    const int b = blockIdx.z;
    const int qa = p, qb = 31 - p;
    const int na = qa + 1, nb = qb + 1;

    const int t    = threadIdx.x;
    const int lane = t & 63;
    const int w    = t >> 6;
    const int lr   = lane & 15;
    const int kg   = lane >> 4;

    const size_t bh = (size_t)b * NH + h;
    const u16* qp = q + bh * SEQ * HD;
    const u16* kp = k + bh * SEQ * HD;
    const u16* vp = v + bh * SEQ * HD;

    {
        const float* Mb = memv + bh * HD * HD;
        #pragma unroll
        for (int u = 0; u < 16; ++u) {
            const int flat = t + (u << 8);           // d*64 + e
            Mt[(flat & 63) * 72 + (flat >> 6)] = f2bf(Mb[flat]);
        }
        if (t < 64) norm_s[t] = normv[bh * HD + t];
    }
    __syncthreads();

    const int rbase0 = qa * 64 + w * 16;
    const int rbase1 = qb * 64 + w * 16;
    short8 qatt[2][2], qmem[2][2];
    float nrrow[2];
    #pragma unroll
    for (int fm = 0; fm < 2; ++fm) {
        const int rb = fm ? rbase1 : rbase0;
        const u16* qrow = qp + (size_t)(rb + lr) * HD;
        float nr = 0.f;
        #pragma unroll
        for (int kk = 0; kk < 2; ++kk) {
            const int dbase = kk * 32 + kg * 8;
            u16x8 raw = *(const u16x8*)(qrow + dbase);
            qatt[fm][kk] = __builtin_bit_cast(short8, raw);
            short8 sm;
            #pragma unroll
            for (int i = 0; i < 8; ++i) {
                const float xx = bf2f(raw[i]);
                const float e = (xx > 0.f) ? (xx + 1.f) : __expf(xx);
                sm[i] = (short)f2bf(e);
                nr = fmaf(e, norm_s[dbase + i], nr);
            }
            qmem[fm][kk] = sm;
        }
        nr += __shfl_xor(nr, 16);
        nr += __shfl_xor(nr, 32);
        nrrow[fm] = nr;
    }

    f32x4 oacc[2][4];
    #pragma unroll
    for (int fm = 0; fm < 2; ++fm)
        #pragma unroll
        for (int fn = 0; fn < 4; ++fn) {
            f32x4 z = {0.f, 0.f, 0.f, 0.f};
            oacc[fm][fn] = z;
        }
    float mrow[2][4], lrow[2][4];
    #pragma unroll
    for (int fm = 0; fm < 2; ++fm)
        #pragma unroll
        for (int r = 0; r < 4; ++r) { mrow[fm][r] = -1e30f; lrow[fm][r] = 0.f; }

    const int pbase = w * 2048;          // 32 rows * 64

    for (int kt = 0; kt < nb; ++kt) {
        __syncthreads();
        // K: async direct to LDS, source-swizzled
        #pragma unroll
        for (int u = 0; u < 2; ++u) {
            const int cid = (u << 8) + t;
            const int row = cid >> 3, c16 = cid & 7;
            const int src = c16 ^ (row & 7);
            gload_lds16(kp + (size_t)(kt * 64 + row) * HD + (src << 3),
                        &Ks[cid << 3]);
        }
        // V: vector load + transposed scatter (bf16, no converts)
        #pragma unroll
        for (int u = 0; u < 2; ++u) {
            const int cid = (u << 8) + t;
            const int row = cid >> 3;
            const int d0  = (cid & 7) << 3;
            u16x8 vv = *(const u16x8*)(vp + (size_t)(kt * 64 + row) * HD + d0);
            #pragma unroll
            for (int j = 0; j < 8; ++j)
                Vt[(d0 + j) * 72 + row] = vv[j];
        }
        __syncthreads();

        const bool doA = (kt < na);

        short8 kf[4][2];
        #pragma unroll
        for (int fn = 0; fn < 4; ++fn)
            #pragma unroll
            for (int kk = 0; kk < 2; ++kk) {
                const int r = fn * 16 + lr;
                const int c = (kk << 2) + kg;
                kf[fn][kk] = *(const short8*)&Ks[r * 64 + (((c) ^ (r & 7)) << 3)];
            }

        auto qk_fm = [&](auto FM_) {
            constexpr int fm = FM_.value;
            const int rb = fm ? rbase1 : rbase0;
            f32x4 S[4];
            #pragma unroll
            for (int fn = 0; fn < 4; ++fn) {
                f32x4 z = {0.f, 0.f, 0.f, 0.f};
                S[fn] = z;
            }
            #pragma unroll
            for (int fn = 0; fn < 4; ++fn)
                #pragma unroll
                for (int kk = 0; kk < 2; ++kk)
                    S[fn] = __builtin_amdgcn_mfma_f32_16x16x32_bf16(
                        qatt[fm][kk], kf[fn][kk], S[fn], 0, 0, 0);

            float sl[4][4];
            float cm[4] = {-1e30f, -1e30f, -1e30f, -1e30f};
            #pragma unroll
            for (int fn = 0; fn < 4; ++fn) {
                const int kgl = kt * 64 + fn * 16 + lr;
                #pragma unroll
                for (int r = 0; r < 4; ++r) {
                    float s = S[fn][r] * (LOG2E * 0.125f);
                    const int qg = rb + kg * 4 + r;
                    if (kgl > qg) s = -1e30f;
                    sl[fn][r] = s;
                    cm[r] = fmaxf(cm[r], s);
                }
            }
            #pragma unroll
            for (int r = 0; r < 4; ++r) {
                cm[r] = fmaxf(cm[r], __shfl_xor(cm[r], 1));
                cm[r] = fmaxf(cm[r], __shfl_xor(cm[r], 2));
                cm[r] = fmaxf(cm[r], __shfl_xor(cm[r], 4));
                cm[r] = fmaxf(cm[r], __shfl_xor(cm[r], 8));
                const float mn = fmaxf(mrow[fm][r], cm[r]);
                const float corr = exp2f(mrow[fm][r] - mn);
                mrow[fm][r] = mn;
                lrow[fm][r] *= corr;
                #pragma unroll
                for (int fn = 0; fn < 4; ++fn) oacc[fm][fn][r] *= corr;
            }
            float rs[4] = {0.f, 0.f, 0.f, 0.f};
            #pragma unroll
            for (int fn = 0; fn < 4; ++fn)
                #pragma unroll
                for (int r = 0; r < 4; ++r) {
                    const float pe = exp2f(sl[fn][r] - mrow[fm][r]);
                    rs[r] += pe;
                    const int row_p = fm * 16 + kg * 4 + r;
                    const int cchunk = ((fn << 1) + (lr >> 3)) ^ (row_p & 7);
                    Ps[pbase + row_p * 64 + (cchunk << 3) + (lr & 7)] = f2bf(pe);
                }
            #pragma unroll
            for (int r = 0; r < 4; ++r) {
                rs[r] += __shfl_xor(rs[r], 1);
                rs[r] += __shfl_xor(rs[r], 2);
                rs[r] += __shfl_xor(rs[r], 4);
                rs[r] += __shfl_xor(rs[r], 8);
                lrow[fm][r] += rs[r];
            }
        };
        if (doA) qk_fm(std::integral_constant<int, 0>{});
        qk_fm(std::integral_constant<int, 1>{});

        short8 vf[4][2];
        #pragma unroll
        for (int fnd = 0; fnd < 4; ++fnd)
            #pragma unroll
            for (int kk = 0; kk < 2; ++kk)
                vf[fnd][kk] = *(const short8*)&Vt[(fnd * 16 + lr) * 72 + kk * 32 + kg * 8];

        auto pv_fm = [&](auto FM_) {
            constexpr int fm = FM_.value;
            short8 pf[2];
            #pragma unroll
            for (int kk = 0; kk < 2; ++kk) {
                const int r = fm * 16 + lr;
                const int c = (kk << 2) + kg;
                pf[kk] = *(const short8*)&Ps[pbase + r * 64 + (((c) ^ (r & 7)) << 3)];
            }
            #pragma unroll
            for (int fnd = 0; fnd < 4; ++fnd)
                #pragma unroll
                for (int kk = 0; kk < 2; ++kk)
                    oacc[fm][fnd] = __builtin_amdgcn_mfma_f32_16x16x32_bf16(
                        pf[kk], vf[fnd][kk], oacc[fm][fnd], 0, 0, 0);
        };
        if (doA) pv_fm(std::integral_constant<int, 0>{});
        pv_fm(std::integral_constant<int, 1>{});
    }

    short8 mf[4][2];
    #pragma unroll
    for (int fn = 0; fn < 4; ++fn)
        #pragma unroll
        for (int kk = 0; kk < 2; ++kk)
            mf[fn][kk] = *(const short8*)&Mt[(fn * 16 + lr) * 72 + kk * 32 + kg * 8];

    f32x4 macc[2][4];
    #pragma unroll
    for (int fm = 0; fm < 2; ++fm)
        #pragma unroll
        for (int fn = 0; fn < 4; ++fn) {
            f32x4 z = {0.f, 0.f, 0.f, 0.f};
            macc[fm][fn] = z;
            #pragma unroll
            for (int kk = 0; kk < 2; ++kk)
                macc[fm][fn] = __builtin_amdgcn_mfma_f32_16x16x32_bf16(
                    qmem[fm][kk], mf[fn][kk], macc[fm][fn], 0, 0, 0);
        }

    const float g  = 1.f / (1.f + __expf(-gatev[h]));
    const float og = 1.f - g;

    #pragma unroll
    for (int fm = 0; fm < 2; ++fm) {
        const int rb = fm ? rbase1 : rbase0;
        #pragma unroll
        for (int r = 0; r < 4; ++r) {
            const int rt  = kg * 4 + r;
            const int src = (lane & 48) | rt;
            const float nrd   = __shfl(nrrow[fm], src);
            const float nrinv = 1.f / (nrd + 1e-6f);
            const float linv  = 1.f / lrow[fm][r];
            const int qg = rb + rt;
            u16* crow = comb + ((size_t)b * SEQ + qg) * DIM + h * HD;
            #pragma unroll
            for (int fn = 0; fn < 4; ++fn)
                crow[fn * 16 + lr] = f2bf(
                    g * (macc[fm][fn][r] * nrinv) + og * (oacc[fm][fn][r] * linv));
        }
    }
}

// ---------------------------------------------------------------------------
// Memory write partials from bf16 k/v
// ---------------------------------------------------------------------------
__global__ __launch_bounds__(256)
void memwrite_part(const u16* __restrict__ k,
                   const u16* __restrict__ v,
                   float* __restrict__ part,
                   float* __restrict__ pnorm)
{
    __shared__ float Kel[64][65];
    __shared__ float Vsm[64][65];

    const int ch = blockIdx.x;
    const int bh = blockIdx.y;
    const int t  = threadIdx.x;
    const int dr = t >> 2;
    const int e0 = (t & 3) << 4;

    const u16* kb = k + (size_t)bh * SEQ * HD + (size_t)ch * 256 * HD;
    const u16* vb = v + (size_t)bh * SEQ * HD + (size_t)ch * 256 * HD;

    float acc[16] = {};
    float nacc = 0.f;

    for (int st = 0; st < 4; ++st) {
        __syncthreads();
        #pragma unroll
        for (int u = 0; u < 2; ++u) {
            const int cid = (u << 8) + t;
            const int row = cid >> 3;
            const int d0  = (cid & 7) << 3;
            u16x8 kv = *(const u16x8*)(kb + (size_t)(st * 64 + row) * HD + d0);
            u16x8 vv = *(const u16x8*)(vb + (size_t)(st * 64 + row) * HD + d0);
            #pragma unroll
            for (int j = 0; j < 8; ++j) {
                const float kf = bf2f(kv[j]);
                Kel[row][d0 + j] = (kf > 0.f) ? kf + 1.f : __expf(kf);
                Vsm[row][d0 + j] = bf2f(vv[j]);
            }
        }
        __syncthreads();
        #pragma unroll 8
        for (int ss = 0; ss < 64; ++ss) {
            const float km = Kel[ss][dr];
            nacc += km;
            #pragma unroll
            for (int j = 0; j < 4; ++j) {
                float4 vv = *(const float4*)&Vsm[ss][e0 + j * 4];
                acc[4*j+0] = fmaf(km, vv.x, acc[4*j+0]);
                acc[4*j+1] = fmaf(km, vv.y, acc[4*j+1]);
                acc[4*j+2] = fmaf(km, vv.z, acc[4*j+2]);
                acc[4*j+3] = fmaf(km, vv.w, acc[4*j+3]);
            }
        }
    }

    float* po = part + (((size_t)bh * 8 + ch) * 64 + dr) * 64 + e0;
    #pragma unroll
    for (int j = 0; j < 4; ++j)
        *(float4*)(po + j * 4) = *(float4*)&acc[4*j];
    if ((t & 3) == 0) pnorm[((size_t)bh * 8 + ch) * 64 + dr] = nacc;
}

__global__ __launch_bounds__(256)
void memwrite_reduce(const float* __restrict__ part,
                     const float* __restrict__ pnorm,
                     const float* __restrict__ memv,
                     const float* __restrict__ normv,
                     float* __restrict__ new_mem,
                     float* __restrict__ new_norm)
{
    const int bh = blockIdx.x;
    const int t  = threadIdx.x;
    #pragma unroll
    for (int u = 0; u < 16; ++u) {
        const int fl = t + (u << 8);
        float s = memv[(size_t)bh * 4096 + fl];
        #pragma unroll
        for (int ch = 0; ch < 8; ++ch)
            s += part[((size_t)bh * 8 + ch) * 4096 + fl];
        new_mem[(size_t)bh * 4096 + fl] = s;
    }
    if (t < 64) {
        float s = normv[(size_t)bh * 64 + t];
        #pragma unroll
        for (int ch = 0; ch < 8; ++ch)
            s += pnorm[((size_t)bh * 8 + ch) * 64 + t];
        new_norm[(size_t)bh * 64 + t] = s;
    }
}

// ---------------------------------------------------------------------------
extern "C" void kernel_launch(void* const* d_in, const int* in_sizes, int n_in,
                              void* d_out, int out_size, void* d_ws, size_t ws_size,
                              hipStream_t stream)
{
    const float* x     = (const float*)d_in[0];
    const float* memv  = (const float*)d_in[1];
    const float* normv = (const float*)d_in[2];
    const float* Wq    = (const float*)d_in[3];
    const float* Wk    = (const float*)d_in[4];
    const float* Wv    = (const float*)d_in[5];
    const float* Wo    = (const float*)d_in[6];
    const float* gate  = (const float*)d_in[7];
    float* out = (float*)d_out;

    // ws layout (bf16 unless noted):
    u16* xbf  = (u16*)d_ws;                    // 2^22 elems (8 MB)
    u16* wbf  = xbf + ((size_t)1 << 22);       // 4 * 2^20    (8 MB)
    u16* qkv  = wbf + ((size_t)4 << 20);       // 3 * 2^22    (24 MB)
    u16* comb = qkv + ((size_t)3 << 22);       // 2^22        (8 MB)
    float* part  = (float*)(comb + ((size_t)1 << 22));   // 2^20 f32 (4 MB)
    float* pnorm = part + ((size_t)1 << 20);             // 2048 f32

    u16* qbf = qkv;
    u16* kbf = qkv + ((size_t)1 << 22);
    u16* vbf = qkv + ((size_t)2 << 22);

    float* new_mem  = out + (size_t)NB * SEQ * DIM;
    float* new_norm = new_mem + (size_t)NB * NH * HD * HD;

    conv_bf16<<<dim3(2048, 5), 256, 0, stream>>>(x, Wq, Wk, Wv, Wo, xbf, wbf);
    gemm_lds<0, 4><<<dim3(32, 8, 3), 256, 0, stream>>>(xbf, wbf, qkv, nullptr);
    attn_mfma<<<dim3(16, 16, 2), 256, 0, stream>>>(qbf, kbf, vbf, memv, normv,
                                                   gate, comb);
    memwrite_part<<<dim3(8, 32), 256, 0, stream>>>(kbf, vbf, part, pnorm);
    memwrite_reduce<<<dim3(32), 256, 0, stream>>>(part, pnorm, memv, normv,
                                                  new_mem, new_norm);
    gemm_lds<1, 2><<<dim3(64, 8, 1), 256, 0, stream>>>(comb, wbf + ((size_t)3 << 20),
                                                       nullptr, out);
}

// Round 5
// 206.417 us; speedup vs baseline: 6.1001x; 1.3135x over previous
//
#include <hip/hip_runtime.h>
#include <hip/hip_bf16.h>
#include <math.h>
#include <type_traits>

#define DIM 1024
#define NH 16
#define HD 64
#define NB 2
#define SEQ 2048

typedef unsigned short u16;
typedef short short8 __attribute__((ext_vector_type(8)));
typedef unsigned short u16x8 __attribute__((ext_vector_type(8)));
typedef float f32x4 __attribute__((ext_vector_type(4)));

#define LOG2E 1.44269504f

__device__ __forceinline__ u16 f2bf(float f) {
    __hip_bfloat16 h = __float2bfloat16(f);
    return __builtin_bit_cast(u16, h);
}
__device__ __forceinline__ float bf2f(u16 u) {
    return __uint_as_float(((unsigned)u) << 16);
}

// global -> LDS direct async copy, 16B per lane. LDS dest linear per wave;
// swizzling done on the SOURCE address (m173 pattern).
__device__ __forceinline__ void gload_lds16(const u16* g, u16* l) {
    __builtin_amdgcn_global_load_lds(
        (const __attribute__((address_space(1))) unsigned int*)g,
        (__attribute__((address_space(3))) unsigned int*)l, 16, 0, 0);
}

// ---------------------------------------------------------------------------
// fp32 -> bf16 conversion pass: y=0: x, y=1..4: Wq/Wk/Wv/Wo
// ---------------------------------------------------------------------------
__global__ __launch_bounds__(256)
void conv_bf16(const float* __restrict__ x,
               const float* __restrict__ wq, const float* __restrict__ wk,
               const float* __restrict__ wv, const float* __restrict__ wo,
               u16* __restrict__ xbf, u16* __restrict__ wbf)
{
    const int y = blockIdx.y;
    const float* src; u16* dst; int n;
    if (y == 0)      { src = x;  dst = xbf;              n = 1 << 22; }
    else if (y == 1) { src = wq; dst = wbf;              n = 1 << 20; }
    else if (y == 2) { src = wk; dst = wbf + (1 << 20);  n = 1 << 20; }
    else if (y == 3) { src = wv; dst = wbf + (2 << 20);  n = 1 << 20; }
    else             { src = wo; dst = wbf + (3 << 20);  n = 1 << 20; }
    const int i8 = (blockIdx.x * 256 + threadIdx.x) * 8;
    if (i8 >= n) return;
    float4 a = *(const float4*)(src + i8);
    float4 b = *(const float4*)(src + i8 + 4);
    u16x8 o;
    o[0] = f2bf(a.x); o[1] = f2bf(a.y); o[2] = f2bf(a.z); o[3] = f2bf(a.w);
    o[4] = f2bf(b.x); o[5] = f2bf(b.y); o[6] = f2bf(b.z); o[7] = f2bf(b.w);
    *(u16x8*)(dst + i8) = o;
}

// ---------------------------------------------------------------------------
// bf16 GEMM via global_load_lds (m97 structure), unchanged from round 4.
// ---------------------------------------------------------------------------
template<int MODE, int FM>
__global__ __launch_bounds__(256)
void gemm_lds(const u16* __restrict__ X, const u16* __restrict__ Wall,
              u16* __restrict__ Obf, float* __restrict__ Of)
{
    constexpr int MT = FM * 32;
    __shared__ u16 As[MT * 64];
    __shared__ u16 Bs[128 * 64];

    const int t    = threadIdx.x;
    const int lane = t & 63;
    const int wave = t >> 6;
    const int wm = wave >> 1, wn = wave & 1;
    const int lr = lane & 15, kg = lane >> 4;
    const int m_base = blockIdx.x * MT;
    const int n_base = blockIdx.y * 128;

    const u16* Xb = X + (size_t)m_base * DIM;
    const u16* Wb = Wall + (MODE == 0 ? ((size_t)blockIdx.z << 20) : (size_t)0)
                         + (size_t)n_base * DIM;

    f32x4 acc[FM][4];
    #pragma unroll
    for (int i = 0; i < FM; ++i)
        #pragma unroll
        for (int j = 0; j < 4; ++j) {
            f32x4 z = {0.f, 0.f, 0.f, 0.f};
            acc[i][j] = z;
        }

    for (int k0 = 0; k0 < DIM; k0 += 64) {
        __syncthreads();
        #pragma unroll
        for (int u = 0; u < FM; ++u) {
            const int cid = (u << 8) + t;
            const int row = cid >> 3, c16 = cid & 7;
            const int src = c16 ^ (row & 7);
            gload_lds16(Xb + (size_t)row * DIM + k0 + (src << 3), &As[cid << 3]);
        }
        #pragma unroll
        for (int u = 0; u < 4; ++u) {
            const int cid = (u << 8) + t;
            const int row = cid >> 3, c16 = cid & 7;
            const int src = c16 ^ (row & 7);
            gload_lds16(Wb + (size_t)row * DIM + k0 + (src << 3), &Bs[cid << 3]);
        }
        __syncthreads();

        #pragma unroll
        for (int kh = 0; kh < 2; ++kh) {
            short8 afrag[FM], bfrag[4];
            #pragma unroll
            for (int fm = 0; fm < FM; ++fm) {
                const int r = wm * (FM * 16) + fm * 16 + lr;
                const int c = (kh << 2) + kg;
                afrag[fm] = *(const short8*)&As[r * 64 + (((c) ^ (r & 7)) << 3)];
            }
            #pragma unroll
            for (int fn = 0; fn < 4; ++fn) {
                const int r = wn * 64 + fn * 16 + lr;
                const int c = (kh << 2) + kg;
                bfrag[fn] = *(const short8*)&Bs[r * 64 + (((c) ^ (r & 7)) << 3)];
            }
            #pragma unroll
            for (int fm = 0; fm < FM; ++fm)
                #pragma unroll
                for (int fn = 0; fn < 4; ++fn)
                    acc[fm][fn] = __builtin_amdgcn_mfma_f32_16x16x32_bf16(
                        afrag[fm], bfrag[fn], acc[fm][fn], 0, 0, 0);
        }
    }

    u16* O0 = (MODE == 0) ? Obf + ((size_t)blockIdx.z << 22) : nullptr;
    #pragma unroll
    for (int fm = 0; fm < FM; ++fm) {
        const int mrow0 = m_base + wm * (FM * 16) + fm * 16 + kg * 4;
        #pragma unroll
        for (int i = 0; i < 4; ++i) {
            const int m = mrow0 + i;
            const int b = m >> 11;
            const int s = m & (SEQ - 1);
            #pragma unroll
            for (int fn = 0; fn < 4; ++fn) {
                const int n = n_base + wn * 64 + fn * 16 + lr;
                const float val = acc[fm][fn][i];
                if (MODE == 0)
                    O0[(((size_t)b * NH + (n >> 6)) * SEQ + s) * HD + (n & 63)] =
                        f2bf(val);
                else
                    Of[((size_t)b * SEQ + s) * DIM + n] = val;
            }
        }
    }
}

// ---------------------------------------------------------------------------
// MFMA flash attention + memory read + gated combine.
// 1024 blocks (qt,h,b) with bijective XCD-grouped heavy-first remap.
// 4 waves, wave w owns 16 q-rows. KV tiles of 64, double-buffered, pipelined
// (T14): issue next K gload_lds + V reg loads before compute; V ds_write after.
// K/V/M all in swizzled-linear LDS (conflict-free reads AND writes).
// ---------------------------------------------------------------------------
__global__ __launch_bounds__(256, 3)
void attn_mfma(const u16* __restrict__ q,
               const u16* __restrict__ k,
               const u16* __restrict__ v,
               const float* __restrict__ memv,
               const float* __restrict__ normv,
               const float* __restrict__ gatev,
               u16* __restrict__ comb)
{
    __shared__ u16 Ks[2][64 * 64];
    __shared__ u16 Vt[2][64 * 64];
    __shared__ u16 Mt[64 * 64];
    __shared__ u16 Ps[4][16 * 64];
    __shared__ float norm_s[64];

    const int t    = threadIdx.x;
    const int lane = t & 63;
    const int w    = t >> 6;
    const int lr   = lane & 15;
    const int kg   = lane >> 4;

    // bijective remap: XCD gets contiguous work chunk; heavy q-tiles first.
    const int lin  = blockIdx.x + 32 * (blockIdx.y + 16 * blockIdx.z);
    const int work = (lin & 7) * 128 + (lin >> 3);
    const int qt   = 31 - (work & 31);
    const int h    = (work >> 5) & 15;
    const int b    = work >> 9;
    const int nkt  = qt + 1;

    const size_t bh = (size_t)b * NH + h;
    const u16* qp = q + bh * SEQ * HD;
    const u16* kp = k + bh * SEQ * HD;
    const u16* vp = v + bh * SEQ * HD;

    auto stageK = [&](int kt, u16* dst) {
        #pragma unroll
        for (int u = 0; u < 2; ++u) {
            const int cid = (u << 8) + t;
            const int row = cid >> 3, c16 = cid & 7;
            const int src = c16 ^ (row & 7);
            gload_lds16(kp + (size_t)(kt * 64 + row) * HD + (src << 3),
                        dst + (cid << 3));
        }
    };
    auto loadV = [&](int kt, u16x8 (&vreg)[2]) {
        #pragma unroll
        for (int u = 0; u < 2; ++u) {
            const int cid = (u << 8) + t;
            const int krow = cid & 63, dc = cid >> 6;
            vreg[u] = *(const u16x8*)(vp + (size_t)(kt * 64 + krow) * HD + (dc << 3));
        }
    };
    // transpose scatter into swizzled layout: elem (d,krow) at
    // d*64 + ((krow>>3 ^ (d&7))<<3) + (krow&7).  With lane=krow, chunk=dc,
    // banks = 4*((krow>>3)^j) + ((krow&7)>>1): all 32 banks, 2 lanes each.
    auto writeV = [&](u16* dst, const u16x8 (&vreg)[2]) {
        #pragma unroll
        for (int u = 0; u < 2; ++u) {
            const int cid = (u << 8) + t;
            const int krow = cid & 63, d0 = (cid >> 6) << 3;
            #pragma unroll
            for (int j = 0; j < 8; ++j)
                dst[(d0 + j) * 64 + (((krow >> 3) ^ j) << 3) + (krow & 7)] =
                    vreg[u][j];
        }
    };

    // ---- stage Mt (transposed, swizzled) + norm ----
    {
        const float* Mb = memv + bh * HD * HD;
        #pragma unroll
        for (int u = 0; u < 2; ++u) {
            const int cid = (u << 8) + t;
            const int gd = cid & 63;
            const int e0 = (cid >> 6) << 3;
            float4 m0 = *(const float4*)(Mb + gd * HD + e0);
            float4 m1 = *(const float4*)(Mb + gd * HD + e0 + 4);
            float mv8[8];
            *(float4*)&mv8[0] = m0; *(float4*)&mv8[4] = m1;
            #pragma unroll
            for (int j = 0; j < 8; ++j)
                Mt[(e0 + j) * 64 + (((gd >> 3) ^ j) << 3) + (gd & 7)] =
                    f2bf(mv8[j]);
        }
        if (t < 64) norm_s[t] = normv[bh * HD + t];
    }
    __syncthreads();

    // ---- Q prologue: attention A-frag (raw) + memory A-frag (elu+1) ----
    const int rb = qt * 64 + w * 16;
    short8 qatt[2], qmem[2];
    float nrrow;
    {
        const u16* qrow = qp + (size_t)(rb + lr) * HD;
        float nr = 0.f;
        #pragma unroll
        for (int kk = 0; kk < 2; ++kk) {
            const int dbase = kk * 32 + kg * 8;
            u16x8 raw = *(const u16x8*)(qrow + dbase);
            qatt[kk] = __builtin_bit_cast(short8, raw);
            short8 sm;
            #pragma unroll
            for (int i = 0; i < 8; ++i) {
                const float xx = bf2f(raw[i]);
                const float e = (xx > 0.f) ? (xx + 1.f) : __expf(xx);
                sm[i] = (short)f2bf(e);
                nr = fmaf(e, norm_s[dbase + i], nr);
            }
            qmem[kk] = sm;
        }
        nr += __shfl_xor(nr, 16);
        nr += __shfl_xor(nr, 32);
        nrrow = nr;
    }

    f32x4 oacc[4];
    #pragma unroll
    for (int fn = 0; fn < 4; ++fn) {
        f32x4 z = {0.f, 0.f, 0.f, 0.f};
        oacc[fn] = z;
    }
    float mrow[4] = {-1e30f, -1e30f, -1e30f, -1e30f};
    float lrow[4] = {0.f, 0.f, 0.f, 0.f};

    // ---- prologue staging of tile 0 ----
    u16x8 vreg[2];
    stageK(0, &Ks[0][0]);
    loadV(0, vreg);
    writeV(&Vt[0][0], vreg);
    __syncthreads();

    // ---- main KV loop, pipelined ----
    for (int kt = 0; kt < nkt; ++kt) {
        const int cur = kt & 1;
        const u16* Kc = &Ks[cur][0];
        const u16* Vc = &Vt[cur][0];

        // K frags for this tile
        short8 kf[4][2];
        #pragma unroll
        for (int fn = 0; fn < 4; ++fn)
            #pragma unroll
            for (int kk = 0; kk < 2; ++kk) {
                const int r = fn * 16 + lr;
                const int c = (kk << 2) + kg;
                kf[fn][kk] = *(const short8*)&Kc[r * 64 + ((c ^ (r & 7)) << 3)];
            }

        // prefetch next tile (issue early; ds_write deferred to after compute)
        const bool more = (kt + 1 < nkt);
        if (more) {
            stageK(kt + 1, &Ks[cur ^ 1][0]);
            loadV(kt + 1, vreg);
        }

        // QK^T
        f32x4 S[4];
        #pragma unroll
        for (int fn = 0; fn < 4; ++fn) {
            f32x4 z = {0.f, 0.f, 0.f, 0.f};
            S[fn] = z;
        }
        #pragma unroll
        for (int fn = 0; fn < 4; ++fn)
            #pragma unroll
            for (int kk = 0; kk < 2; ++kk)
                S[fn] = __builtin_amdgcn_mfma_f32_16x16x32_bf16(
                    qatt[kk], kf[fn][kk], S[fn], 0, 0, 0);

        // logits + causal mask (only diagonal tile needs it)
        float sl[4][4];
        float cm[4] = {-1e30f, -1e30f, -1e30f, -1e30f};
        const bool diag = (kt == qt);
        #pragma unroll
        for (int fn = 0; fn < 4; ++fn) {
            const int kgl = kt * 64 + fn * 16 + lr;
            #pragma unroll
            for (int r = 0; r < 4; ++r) {
                float s = S[fn][r] * (LOG2E * 0.125f);
                if (diag && kgl > rb + kg * 4 + r) s = -1e30f;
                sl[fn][r] = s;
                cm[r] = fmaxf(cm[r], s);
            }
        }
        #pragma unroll
        for (int r = 0; r < 4; ++r) {
            cm[r] = fmaxf(cm[r], __shfl_xor(cm[r], 1));
            cm[r] = fmaxf(cm[r], __shfl_xor(cm[r], 2));
            cm[r] = fmaxf(cm[r], __shfl_xor(cm[r], 4));
            cm[r] = fmaxf(cm[r], __shfl_xor(cm[r], 8));
        }
        // defer-max (T13): rescale only if some row grew > 8 (log2 units)
        const float growth = fmaxf(fmaxf(cm[0] - mrow[0], cm[1] - mrow[1]),
                                   fmaxf(cm[2] - mrow[2], cm[3] - mrow[3]));
        if (!__all(growth <= 8.f)) {
            #pragma unroll
            for (int r = 0; r < 4; ++r) {
                const float mn = fmaxf(mrow[r], cm[r]);
                const float corr = exp2f(mrow[r] - mn);
                mrow[r] = mn;
                lrow[r] *= corr;
                #pragma unroll
                for (int fn = 0; fn < 4; ++fn) oacc[fn][r] *= corr;
            }
        }
        // P = exp2, store to per-wave swizzled LDS, accumulate row sums
        float rs[4] = {0.f, 0.f, 0.f, 0.f};
        #pragma unroll
        for (int fn = 0; fn < 4; ++fn)
            #pragma unroll
            for (int r = 0; r < 4; ++r) {
                const float pe = exp2f(sl[fn][r] - mrow[r]);
                rs[r] += pe;
                const int row_p = kg * 4 + r;
                const int cc = ((fn << 1) + (lr >> 3)) ^ (row_p & 7);
                Ps[w][row_p * 64 + (cc << 3) + (lr & 7)] = f2bf(pe);
            }
        #pragma unroll
        for (int r = 0; r < 4; ++r) {
            rs[r] += __shfl_xor(rs[r], 1);
            rs[r] += __shfl_xor(rs[r], 2);
            rs[r] += __shfl_xor(rs[r], 4);
            rs[r] += __shfl_xor(rs[r], 8);
            lrow[r] += rs[r];
        }

        // PV
        short8 pf[2], vf[4][2];
        #pragma unroll
        for (int kk = 0; kk < 2; ++kk) {
            const int c = (kk << 2) + kg;
            pf[kk] = *(const short8*)&Ps[w][lr * 64 + ((c ^ (lr & 7)) << 3)];
        }
        #pragma unroll
        for (int fnd = 0; fnd < 4; ++fnd)
            #pragma unroll
            for (int kk = 0; kk < 2; ++kk) {
                const int d = fnd * 16 + lr;
                const int c = (kk << 2) + kg;
                vf[fnd][kk] = *(const short8*)&Vc[d * 64 + ((c ^ (d & 7)) << 3)];
            }
        #pragma unroll
        for (int fnd = 0; fnd < 4; ++fnd)
            #pragma unroll
            for (int kk = 0; kk < 2; ++kk)
                oacc[fnd] = __builtin_amdgcn_mfma_f32_16x16x32_bf16(
                    pf[kk], vf[fnd][kk], oacc[fnd], 0, 0, 0);

        // deferred V write for next tile (after compute: HBM latency hidden)
        __builtin_amdgcn_sched_barrier(0);
        if (more) writeV(&Vt[cur ^ 1][0], vreg);
        __syncthreads();
    }

    // ---- epilogue: memory read via MFMA ----
    short8 mf2[4][2];
    #pragma unroll
    for (int fn = 0; fn < 4; ++fn)
        #pragma unroll
        for (int kk = 0; kk < 2; ++kk) {
            const int r = fn * 16 + lr;
            const int c = (kk << 2) + kg;
            mf2[fn][kk] = *(const short8*)&Mt[r * 64 + ((c ^ (r & 7)) << 3)];
        }
    f32x4 macc[4];
    #pragma unroll
    for (int fn = 0; fn < 4; ++fn) {
        f32x4 z = {0.f, 0.f, 0.f, 0.f};
        macc[fn] = z;
        #pragma unroll
        for (int kk = 0; kk < 2; ++kk)
            macc[fn] = __builtin_amdgcn_mfma_f32_16x16x32_bf16(
                qmem[kk], mf2[fn][kk], macc[fn], 0, 0, 0);
    }

    const float g  = 1.f / (1.f + __expf(-gatev[h]));
    const float og = 1.f - g;

    #pragma unroll
    for (int r = 0; r < 4; ++r) {
        const int rt  = kg * 4 + r;
        const int src = (lane & 48) | rt;
        const float nrd   = __shfl(nrrow, src);
        const float nrinv = 1.f / (nrd + 1e-6f);
        const float linv  = 1.f / lrow[r];
        const int qg = rb + rt;
        u16* crow = comb + ((size_t)b * SEQ + qg) * DIM + h * HD;
        #pragma unroll
        for (int fn = 0; fn < 4; ++fn)
            crow[fn * 16 + lr] = f2bf(
                g * (macc[fn][r] * nrinv) + og * (oacc[fn][r] * linv));
    }
}

// ---------------------------------------------------------------------------
// Memory write partials from bf16 k/v
// ---------------------------------------------------------------------------
__global__ __launch_bounds__(256)
void memwrite_part(const u16* __restrict__ k,
                   const u16* __restrict__ v,
                   float* __restrict__ part,
                   float* __restrict__ pnorm)
{
    __shared__ float Kel[64][65];
    __shared__ float Vsm[64][65];

    const int ch = blockIdx.x;
    const int bh = blockIdx.y;
    const int t  = threadIdx.x;
    const int dr = t >> 2;
    const int e0 = (t & 3) << 4;

    const u16* kb = k + (size_t)bh * SEQ * HD + (size_t)ch * 256 * HD;
    const u16* vb = v + (size_t)bh * SEQ * HD + (size_t)ch * 256 * HD;

    float acc[16] = {};
    float nacc = 0.f;

    for (int st = 0; st < 4; ++st) {
        __syncthreads();
        #pragma unroll
        for (int u = 0; u < 2; ++u) {
            const int cid = (u << 8) + t;
            const int row = cid >> 3;
            const int d0  = (cid & 7) << 3;
            u16x8 kv = *(const u16x8*)(kb + (size_t)(st * 64 + row) * HD + d0);
            u16x8 vv = *(const u16x8*)(vb + (size_t)(st * 64 + row) * HD + d0);
            #pragma unroll
            for (int j = 0; j < 8; ++j) {
                const float kf = bf2f(kv[j]);
                Kel[row][d0 + j] = (kf > 0.f) ? kf + 1.f : __expf(kf);
                Vsm[row][d0 + j] = bf2f(vv[j]);
            }
        }
        __syncthreads();
        #pragma unroll 8
        for (int ss = 0; ss < 64; ++ss) {
            const float km = Kel[ss][dr];
            nacc += km;
            #pragma unroll
            for (int j = 0; j < 4; ++j) {
                float4 vv = *(const float4*)&Vsm[ss][e0 + j * 4];
                acc[4*j+0] = fmaf(km, vv.x, acc[4*j+0]);
                acc[4*j+1] = fmaf(km, vv.y, acc[4*j+1]);
                acc[4*j+2] = fmaf(km, vv.z, acc[4*j+2]);
                acc[4*j+3] = fmaf(km, vv.w, acc[4*j+3]);
            }
        }
    }

    float* po = part + (((size_t)bh * 8 + ch) * 64 + dr) * 64 + e0;
    #pragma unroll
    for (int j = 0; j < 4; ++j)
        *(float4*)(po + j * 4) = *(float4*)&acc[4*j];
    if ((t & 3) == 0) pnorm[((size_t)bh * 8 + ch) * 64 + dr] = nacc;
}

__global__ __launch_bounds__(256)
void memwrite_reduce(const float* __restrict__ part,
                     const float* __restrict__ pnorm,
                     const float* __restrict__ memv,
                     const float* __restrict__ normv,
                     float* __restrict__ new_mem,
                     float* __restrict__ new_norm)
{
    const int bh = blockIdx.x;
    const int t  = threadIdx.x;
    #pragma unroll
    for (int u = 0; u < 16; ++u) {
        const int fl = t + (u << 8);
        float s = memv[(size_t)bh * 4096 + fl];
        #pragma unroll
        for (int ch = 0; ch < 8; ++ch)
            s += part[((size_t)bh * 8 + ch) * 4096 + fl];
        new_mem[(size_t)bh * 4096 + fl] = s;
    }
    if (t < 64) {
        float s = normv[(size_t)bh * 64 + t];
        #pragma unroll
        for (int ch = 0; ch < 8; ++ch)
            s += pnorm[((size_t)bh * 8 + ch) * 64 + t];
        new_norm[(size_t)bh * 64 + t] = s;
    }
}

// ---------------------------------------------------------------------------
extern "C" void kernel_launch(void* const* d_in, const int* in_sizes, int n_in,
                              void* d_out, int out_size, void* d_ws, size_t ws_size,
                              hipStream_t stream)
{
    const float* x     = (const float*)d_in[0];
    const float* memv  = (const float*)d_in[1];
    const float* normv = (const float*)d_in[2];
    const float* Wq    = (const float*)d_in[3];
    const float* Wk    = (const float*)d_in[4];
    const float* Wv    = (const float*)d_in[5];
    const float* Wo    = (const float*)d_in[6];
    const float* gate  = (const float*)d_in[7];
    float* out = (float*)d_out;

    u16* xbf  = (u16*)d_ws;                    // 2^22 elems
    u16* wbf  = xbf + ((size_t)1 << 22);       // 4 * 2^20
    u16* qkv  = wbf + ((size_t)4 << 20);       // 3 * 2^22
    u16* comb = qkv + ((size_t)3 << 22);       // 2^22
    float* part  = (float*)(comb + ((size_t)1 << 22));   // 2^20 f32
    float* pnorm = part + ((size_t)1 << 20);             // 2048 f32

    u16* qbf = qkv;
    u16* kbf = qkv + ((size_t)1 << 22);
    u16* vbf = qkv + ((size_t)2 << 22);

    float* new_mem  = out + (size_t)NB * SEQ * DIM;
    float* new_norm = new_mem + (size_t)NB * NH * HD * HD;

    conv_bf16<<<dim3(2048, 5), 256, 0, stream>>>(x, Wq, Wk, Wv, Wo, xbf, wbf);
    gemm_lds<0, 4><<<dim3(32, 8, 3), 256, 0, stream>>>(xbf, wbf, qkv, nullptr);
    attn_mfma<<<dim3(32, 16, 2), 256, 0, stream>>>(qbf, kbf, vbf, memv, normv,
                                                   gate, comb);
    memwrite_part<<<dim3(8, 32), 256, 0, stream>>>(kbf, vbf, part, pnorm);
    memwrite_reduce<<<dim3(32), 256, 0, stream>>>(part, pnorm, memv, normv,
                                                  new_mem, new_norm);
    gemm_lds<1, 2><<<dim3(64, 8, 1), 256, 0, stream>>>(comb, wbf + ((size_t)3 << 20),
                                                       nullptr, out);
}